// Round 2
// baseline (7994.616 us; speedup 1.0000x reference)
//
#include <hip/hip_runtime.h>
#include <math.h>

#define NN   10000      // nodes
#define DD   512        // node dim
#define NH   8          // node heads (DK=64)
#define NE   120000     // edges (global)
#define NEL  60000      // local edges
#define NLG  600000     // line-graph edges
#define ED   64         // edge dim (EH=8, EDK=8)
#define NEH  8
#define NL   4          // layers

// ---------------- elementwise helpers ----------------
static __global__ __launch_bounds__(256)
void zero_k(float* __restrict__ p, int n) {
    int i = blockIdx.x * 256 + threadIdx.x;
    if (i < n) p[i] = 0.0f;
}

static __global__ __launch_bounds__(256)
void copy_k(const float* __restrict__ s, float* __restrict__ d, int n) {
    int i = blockIdx.x * 256 + threadIdx.x;
    if (i < n) d[i] = s[i];
}

static __global__ __launch_bounds__(256)
void init_lg_k(const float* __restrict__ rel, const int* __restrict__ ef,
               float* __restrict__ lg) {
    int i = blockIdx.x * 256 + threadIdx.x;
    if (i >= NE * ED) return;
    int e = i >> 6, c = i & 63;
    lg[i] = rel[ef[e] * ED + c];
}

static __global__ __launch_bounds__(256)
void gather64_k(const float* __restrict__ src, const int* __restrict__ idx,
                float* __restrict__ dst, int rows) {
    int i = blockIdx.x * 256 + threadIdx.x;
    if (i >= rows * ED) return;
    int r = i >> 6;
    dst[i] = src[(long)idx[r] * ED + (i & 63)];
}

// ---------------- generic fp32 GEMM ----------------
// C[M,Nc] = op(A)[M,K] @ B[K,Nc] (+bias[Nc]) (relu?) (+addC[M,Nc])
// A rows optionally indirected through rowIdx (gather-GEMM).
// Requires K % 16 == 0, Nc % 64 == 0 (true for all shapes here).
static __global__ __launch_bounds__(256)
void gemm_f32_k(const float* __restrict__ A, const int* __restrict__ rowIdx,
                const float* __restrict__ B, const float* __restrict__ bias,
                const float* __restrict__ addC, float* __restrict__ C,
                int M, int K, int Nc, int doRelu)
{
    __shared__ float As[16][68];   // 68-stride: rows 16B-aligned, conflict-free
    __shared__ float Bs[16][64];
    const int bm = blockIdx.y * 64;
    const int bn = blockIdx.x * 64;
    const int tid = threadIdx.x;
    const int tx = tid & 15;       // output col group
    const int ty = tid >> 4;       // output row group
    const int arow = tid >> 2;     // A-tile loader: row 0..63
    const int acol = (tid & 3) << 2; // k offset 0,4,8,12
    const int brow = tid >> 4;     // B-tile loader: k row 0..15
    const int bcol = (tid & 15) << 2;
    float acc[4][4] = {};

    const int aRowG = bm + arow;
    long aSrc = -1;
    if (aRowG < M) aSrc = rowIdx ? (long)rowIdx[aRowG] : (long)aRowG;

    for (int k0 = 0; k0 < K; k0 += 16) {
        float4 av = make_float4(0.f, 0.f, 0.f, 0.f);
        if (aSrc >= 0)
            av = *reinterpret_cast<const float4*>(A + aSrc * (long)K + k0 + acol);
        As[acol + 0][arow] = av.x;
        As[acol + 1][arow] = av.y;
        As[acol + 2][arow] = av.z;
        As[acol + 3][arow] = av.w;
        *reinterpret_cast<float4*>(&Bs[brow][bcol]) =
            *reinterpret_cast<const float4*>(B + (long)(k0 + brow) * Nc + bn + bcol);
        __syncthreads();
        #pragma unroll
        for (int kk = 0; kk < 16; ++kk) {
            float4 a4 = *reinterpret_cast<const float4*>(&As[kk][ty << 2]);
            float4 b4 = *reinterpret_cast<const float4*>(&Bs[kk][tx << 2]);
            float a[4] = {a4.x, a4.y, a4.z, a4.w};
            float b[4] = {b4.x, b4.y, b4.z, b4.w};
            #pragma unroll
            for (int ii = 0; ii < 4; ++ii)
                #pragma unroll
                for (int jj = 0; jj < 4; ++jj)
                    acc[ii][jj] = fmaf(a[ii], b[jj], acc[ii][jj]);
        }
        __syncthreads();
    }

    #pragma unroll
    for (int ii = 0; ii < 4; ++ii) {
        int m = bm + (ty << 2) + ii;
        if (m >= M) continue;
        #pragma unroll
        for (int jj = 0; jj < 4; ++jj) {
            int n = bn + (tx << 2) + jj;
            float v = acc[ii][jj];
            if (bias) v += bias[n];
            if (doRelu) v = fmaxf(v, 0.0f);
            if (addC) v += addC[(long)m * Nc + n];
            C[(long)m * Nc + n] = v;
        }
    }
}

// ---------------- LayerNorm (one wave per row) ----------------
// out = LN(in) * g + b ; optional secondary scatter out2[idx2[row]] = out
static __global__ __launch_bounds__(64)
void ln_k(const float* __restrict__ in, const float* __restrict__ g,
          const float* __restrict__ b, float* __restrict__ out, int Dw,
          float* __restrict__ out2, const int* __restrict__ idx2)
{
    const int row = blockIdx.x;
    const int lane = threadIdx.x;
    const int per = Dw >> 6;   // 8 for D=512, 1 for D=64
    float v[8];
    const float* rp = in + (long)row * Dw;
    float s = 0.f;
    for (int i = 0; i < per; ++i) { v[i] = rp[i * 64 + lane]; s += v[i]; }
    #pragma unroll
    for (int off = 32; off; off >>= 1) s += __shfl_xor(s, off, 64);
    const float mu = s / (float)Dw;
    float var = 0.f;
    for (int i = 0; i < per; ++i) { float d = v[i] - mu; var += d * d; }
    #pragma unroll
    for (int off = 32; off; off >>= 1) var += __shfl_xor(var, off, 64);
    const float rstd = rsqrtf(var / (float)Dw + 1e-5f);
    for (int i = 0; i < per; ++i) {
        int c = i * 64 + lane;
        float o = (v[i] - mu) * rstd * g[c] + b[c];
        out[(long)row * Dw + c] = o;
        if (out2) out2[(long)idx2[row] * Dw + c] = o;
    }
}

// ---------------- node-level edge attention ----------------
// one wave per edge; lane = dim within head; loop over 8 heads
static __global__ __launch_bounds__(256)
void node_attn_k(const float* __restrict__ q, const float* __restrict__ k,
                 const float* __restrict__ v, const float* __restrict__ lg,
                 const int* __restrict__ gsrc, const int* __restrict__ gdst,
                 float* __restrict__ wv, float* __restrict__ z)
{
    int e = blockIdx.x * 4 + (threadIdx.x >> 6);
    if (e >= NE) return;
    int lane = threadIdx.x & 63;
    int s = gsrc[e], d = gdst[e];
    float ed = lg[(long)e * ED + lane];
    const float* kp = k + (long)s * DD;
    const float* qp = q + (long)d * DD;
    const float* vp = v + (long)s * DD;
    float* wvp = wv + (long)d * DD;
    #pragma unroll
    for (int h = 0; h < NH; ++h) {
        float ks = kp[h * 64 + lane] + ed;
        float p = ks * qp[h * 64 + lane];
        #pragma unroll
        for (int off = 32; off; off >>= 1) p += __shfl_xor(p, off, 64);
        float sc = p * 0.125f;                     // / sqrt(64)
        sc = fminf(fmaxf(sc, -10.0f), 10.0f);
        float w = expf(sc);
        atomicAdd(&wvp[h * 64 + lane], w * (vp[h * 64 + lane] + ed));
        if (lane == 0) atomicAdd(&z[(long)d * NH + h], w);
    }
}

static __global__ __launch_bounds__(256)
void div_node_k(float* __restrict__ wv, const float* __restrict__ z) {
    int i = blockIdx.x * 256 + threadIdx.x;
    if (i >= NN * DD) return;
    int node = i >> 9;
    int h = (i >> 6) & 7;
    wv[i] /= fmaxf(z[node * NH + h], 1e-9f);
}

// ---------------- line-graph attention ----------------
// one wave per lg-edge; lane = h*8+d ; 8-lane group reduce per head
static __global__ __launch_bounds__(256)
void lg_attn_k(const float* __restrict__ qe, const float* __restrict__ ke,
               const float* __restrict__ ve, const int* __restrict__ lsrc,
               const int* __restrict__ ldst, float* __restrict__ wve,
               float* __restrict__ ze)
{
    int m = blockIdx.x * 4 + (threadIdx.x >> 6);
    if (m >= NLG) return;
    int lane = threadIdx.x & 63;
    int s = lsrc[m], d = ldst[m];
    float p = ke[(long)s * ED + lane] * qe[(long)d * ED + lane];
    p += __shfl_xor(p, 1, 64);
    p += __shfl_xor(p, 2, 64);
    p += __shfl_xor(p, 4, 64);
    float sc = p * 0.35355339059327373f;           // / sqrt(8)
    sc = fminf(fmaxf(sc, -10.0f), 10.0f);
    float w = expf(sc);
    atomicAdd(&wve[(long)d * ED + lane], w * ve[(long)s * ED + lane]);
    if ((lane & 7) == 0) atomicAdd(&ze[(long)d * NEH + (lane >> 3)], w);
}

static __global__ __launch_bounds__(256)
void div_edge_k(float* __restrict__ wve, const float* __restrict__ ze) {
    int i = blockIdx.x * 256 + threadIdx.x;
    if (i >= NEL * ED) return;
    int e = i >> 6;
    int h = (i >> 3) & 7;
    wve[i] /= fmaxf(ze[e * NEH + h], 1e-9f);
}

// ---------------- host ----------------
static inline void run_gemm(hipStream_t st, const float* A, const int* idx,
                            const float* B, const float* bias, const float* addC,
                            float* C, int M, int K, int Nc, int relu)
{
    dim3 g(Nc / 64, (M + 63) / 64);
    gemm_f32_k<<<g, 256, 0, st>>>(A, idx, B, bias, addC, C, M, K, Nc, relu);
}

extern "C" void kernel_launch(void* const* d_in, const int* in_sizes, int n_in,
                              void* d_out, int out_size, void* d_ws, size_t ws_size,
                              hipStream_t stream)
{
    const float* x_in  = (const float*)d_in[0];
    const float* rel   = (const float*)d_in[1];
    const float* Wq    = (const float*)d_in[2];
    const float* bq    = (const float*)d_in[3];
    const float* Wk    = (const float*)d_in[4];
    const float* Wv    = (const float*)d_in[5];
    const float* Wo    = (const float*)d_in[6];
    const float* bo    = (const float*)d_in[7];
    const float* ln1g  = (const float*)d_in[8];
    const float* ln1b  = (const float*)d_in[9];
    const float* F1    = (const float*)d_in[10];
    const float* f1b   = (const float*)d_in[11];
    const float* F2    = (const float*)d_in[12];
    const float* f2b   = (const float*)d_in[13];
    const float* ln2g  = (const float*)d_in[14];
    const float* ln2b  = (const float*)d_in[15];
    const float* Eq    = (const float*)d_in[16];
    const float* eqb   = (const float*)d_in[17];
    const float* Ek    = (const float*)d_in[18];
    const float* Ev    = (const float*)d_in[19];
    const float* Eo    = (const float*)d_in[20];
    const float* eob   = (const float*)d_in[21];
    const float* Ns    = (const float*)d_in[22];
    const float* nsb   = (const float*)d_in[23];
    const float* Nd    = (const float*)d_in[24];
    const float* ndb   = (const float*)d_in[25];
    const float* eln1g = (const float*)d_in[26];
    const float* eln1b = (const float*)d_in[27];
    const float* G1    = (const float*)d_in[28];
    const float* g1b   = (const float*)d_in[29];
    const float* G2    = (const float*)d_in[30];
    const float* g2b   = (const float*)d_in[31];
    const float* eln2g = (const float*)d_in[32];
    const float* eln2b = (const float*)d_in[33];
    const int* edge_feat   = (const int*)d_in[34];
    const int* local_index = (const int*)d_in[35];
    const int* src_ids     = (const int*)d_in[36];
    const int* dst_ids     = (const int*)d_in[37];
    const int* g_src       = (const int*)d_in[38];
    const int* g_dst       = (const int*)d_in[39];
    const int* lg_src      = (const int*)d_in[40];
    const int* lg_dst      = (const int*)d_in[41];

    // x and el live in d_out (they ARE the outputs); fully rewritten per call.
    float* xbuf = (float*)d_out;                       // (NN, DD)
    float* el   = xbuf + (size_t)NN * DD;              // (NEL, ED)

    // workspace: ~32.6M floats = ~130 MB
    float* W = (float*)d_ws;
    size_t off = 0;
    auto alloc = [&](size_t n) { float* p = W + off; off += (n + 63) & ~(size_t)63; return p; };
    float* t0 = alloc((size_t)NN * DD);    // q -> h
    float* t1 = alloc((size_t)NN * DD);    // k -> me/wve/oe -> gf/ff
    float* t2 = alloc((size_t)NN * DD);    // v -> ke/he
    float* t3 = alloc((size_t)NN * DD);    // wv -> ve/out_pre
    float* e4 = alloc((size_t)NEL * ED);   // qe
    float* zb = alloc((size_t)NN * NH);
    float* ze = alloc((size_t)NEL * NEH);
    float* lg = alloc((size_t)NE * ED);

    const int ndD = NN * DD;
    const int elD = NEL * ED;
    copy_k<<<(ndD + 255) / 256, 256, 0, stream>>>(x_in, xbuf, ndD);
    init_lg_k<<<(NE * ED + 255) / 256, 256, 0, stream>>>(rel, edge_feat, lg);
    gather64_k<<<(elD + 255) / 256, 256, 0, stream>>>(lg, local_index, el, NEL);

    for (int i = 0; i < NL; ++i) {
        const float* Wq_i = Wq + (size_t)i * DD * DD;
        const float* Wk_i = Wk + (size_t)i * DD * DD;
        const float* Wv_i = Wv + (size_t)i * DD * DD;
        const float* Wo_i = Wo + (size_t)i * DD * DD;
        const float* F1_i = F1 + (size_t)i * DD * 4 * DD;
        const float* F2_i = F2 + (size_t)i * 4 * DD * DD;
        const float* Eq_i = Eq + (size_t)i * ED * ED;
        const float* Ek_i = Ek + (size_t)i * ED * ED;
        const float* Ev_i = Ev + (size_t)i * ED * ED;
        const float* Eo_i = Eo + (size_t)i * ED * ED;
        const float* Ns_i = Ns + (size_t)i * DD * ED;
        const float* Nd_i = Nd + (size_t)i * DD * ED;
        const float* G1_i = G1 + (size_t)i * ED * 4 * ED;
        const float* G2_i = G2 + (size_t)i * 4 * ED * ED;

        // ---- node attention (uses lg BEFORE this layer's edge update) ----
        run_gemm(stream, xbuf, nullptr, Wq_i, bq + (size_t)i * DD, nullptr, t0, NN, DD, DD, 0);
        run_gemm(stream, xbuf, nullptr, Wk_i, nullptr, nullptr, t1, NN, DD, DD, 0);
        run_gemm(stream, xbuf, nullptr, Wv_i, nullptr, nullptr, t2, NN, DD, DD, 0);
        zero_k<<<(ndD + 255) / 256, 256, 0, stream>>>(t3, ndD);
        zero_k<<<(NN * NH + 255) / 256, 256, 0, stream>>>(zb, NN * NH);
        node_attn_k<<<NE / 4, 256, 0, stream>>>(t0, t1, t2, lg, g_src, g_dst, t3, zb);
        div_node_k<<<(ndD + 255) / 256, 256, 0, stream>>>(t3, zb);
        // h = LN(x_in + o @ Wo + bo)   (overwrite q's buffer; q,k,v dead after)
        run_gemm(stream, t3, nullptr, Wo_i, bo + (size_t)i * DD, xbuf, t0, NN, DD, DD, 0);
        ln_k<<<NN, 64, 0, stream>>>(t0, ln1g + (size_t)i * DD, ln1b + (size_t)i * DD, t0, DD, nullptr, nullptr);

        // ---- edge branch (reads xbuf = x_in; el/lg old values) ----
        run_gemm(stream, xbuf, dst_ids, Nd_i, ndb + (size_t)i * ED, nullptr, t1, NEL, DD, ED, 0);   // me
        run_gemm(stream, xbuf, src_ids, Ns_i, nsb + (size_t)i * ED, nullptr, e4, NEL, DD, ED, 0);
        run_gemm(stream, el, nullptr, Eq_i, eqb + (size_t)i * ED, e4, e4, NEL, ED, ED, 0);          // qe
        run_gemm(stream, el, nullptr, Ek_i, nullptr, t1, t2, NEL, ED, ED, 0);                       // ke
        run_gemm(stream, el, nullptr, Ev_i, nullptr, t1, t3, NEL, ED, ED, 0);                       // ve
        zero_k<<<(elD + 255) / 256, 256, 0, stream>>>(t1, elD);
        zero_k<<<(NEL * NEH + 255) / 256, 256, 0, stream>>>(ze, NEL * NEH);
        lg_attn_k<<<NLG / 4, 256, 0, stream>>>(e4, t2, t3, lg_src, lg_dst, t1, ze);
        div_edge_k<<<(elD + 255) / 256, 256, 0, stream>>>(t1, ze);
        // he = LN(el + oe @ Eo + eob)
        run_gemm(stream, t1, nullptr, Eo_i, eob + (size_t)i * ED, el, t2, NEL, ED, ED, 0);
        ln_k<<<NEL, 64, 0, stream>>>(t2, eln1g + (size_t)i * ED, eln1b + (size_t)i * ED, t2, ED, nullptr, nullptr);
        // edge FFN, 3 chunks of 20000 rows (gf = t1, 20000*256 = 5.12M floats)
        for (int c = 0; c < 3; ++c) {
            size_t ro = (size_t)c * 20000;
            run_gemm(stream, t2 + ro * ED, nullptr, G1_i, g1b + (size_t)i * 4 * ED, nullptr, t1, 20000, ED, 4 * ED, 1);
            run_gemm(stream, t1, nullptr, G2_i, g2b + (size_t)i * ED, t2 + ro * ED, t3 + ro * ED, 20000, 4 * ED, ED, 0);
        }
        // out_local = LN(...) -> el, scatter into lg[local_index]
        ln_k<<<NEL, 64, 0, stream>>>(t3, eln2g + (size_t)i * ED, eln2b + (size_t)i * ED, el, ED, lg, local_index);

        // ---- node FFN (x_in dead now: write x in place), 4 chunks of 2500 rows ----
        for (int c = 0; c < 4; ++c) {
            size_t ro = (size_t)c * 2500;
            run_gemm(stream, t0 + ro * DD, nullptr, F1_i, f1b + (size_t)i * 4 * DD, nullptr, t1, 2500, DD, 4 * DD, 1);
            run_gemm(stream, t1, nullptr, F2_i, f2b + (size_t)i * DD, t0 + ro * DD, xbuf + ro * DD, 2500, 4 * DD, DD, 0);
        }
        ln_k<<<NN, 64, 0, stream>>>(xbuf, ln2g + (size_t)i * DD, ln2b + (size_t)i * DD, xbuf, DD, nullptr, nullptr);
    }
    // outputs already in d_out (xbuf, el)
}

// Round 3
// 5596.333 us; speedup vs baseline: 1.4285x; 1.4285x over previous
//
#include <hip/hip_runtime.h>
#include <math.h>

#define NN   10000      // nodes
#define DD   512        // node dim
#define NH   8          // node heads (DK=64)
#define NE   120000     // edges (global)
#define NEL  60000      // local edges
#define NLG  600000     // line-graph edges
#define ED   64         // edge dim (EH=8, EDK=8)
#define NEH  8
#define NL   4          // layers

typedef __attribute__((ext_vector_type(8))) short bf16x8;
typedef __attribute__((ext_vector_type(4))) float f32x4;

__device__ __forceinline__ unsigned short f2b(float f) {
    union { float f; unsigned u; } c; c.f = f;
    unsigned u = c.u;
    unsigned r = u + 0x7FFFu + ((u >> 16) & 1u);
    return (unsigned short)(r >> 16);
}
__device__ __forceinline__ float b2f(unsigned short b) {
    union { unsigned u; float f; } c; c.u = ((unsigned)b) << 16;
    return c.f;
}

// ---------------- elementwise helpers ----------------
static __global__ __launch_bounds__(256)
void zero_k(float* __restrict__ p, int n) {
    int i = blockIdx.x * 256 + threadIdx.x;
    if (i < n) p[i] = 0.0f;
}

// d = s (f32) and db = bf16(s)
static __global__ __launch_bounds__(256)
void castcopy_k(const float* __restrict__ s, float* __restrict__ d,
                unsigned short* __restrict__ db, int n) {
    int i = blockIdx.x * 256 + threadIdx.x;
    if (i < n) { float v = s[i]; if (d) d[i] = v; db[i] = f2b(v); }
}

static __global__ __launch_bounds__(256)
void init_lg_k(const float* __restrict__ rel, const int* __restrict__ ef,
               unsigned short* __restrict__ lgb) {
    int i = blockIdx.x * 256 + threadIdx.x;
    if (i >= NE * ED) return;
    int e = i >> 6, c = i & 63;
    lgb[i] = f2b(rel[ef[e] * ED + c]);
}

// el (f32) and elb (bf16) gathered from lgb
static __global__ __launch_bounds__(256)
void gather64_k(const unsigned short* __restrict__ lgb, const int* __restrict__ idx,
                float* __restrict__ el, unsigned short* __restrict__ elb) {
    int i = blockIdx.x * 256 + threadIdx.x;
    if (i >= NEL * ED) return;
    int r = i >> 6;
    unsigned short b = lgb[(long)idx[r] * ED + (i & 63)];
    el[i] = b2f(b); elb[i] = b;
}

// weight transpose+cast: in[l][K][N] f32 -> out[l][N][K] bf16
static __global__ __launch_bounds__(256)
void tcast_k(const float* __restrict__ in, unsigned short* __restrict__ out,
             int K, int N, int Ln) {
    int i = blockIdx.x * 256 + threadIdx.x;
    int per = K * N;
    if (i >= Ln * per) return;
    int l = i / per, r = i - l * per;
    int n = r / K, k = r - n * K;
    out[i] = f2b(in[(long)l * per + (long)k * N + n]);
}

// ---------------- bf16 MFMA GEMM ----------------
// C[M,Nc] = A[M,K]bf16 (opt row-gather) @ Bt[Nc,K]bf16^T  (+bias)(relu)(+addC)
// out: C fp32 OR Cb bf16. Tile 128x128, BK=32, 256 thr = 4 waves (2x2 of 64x64).
static __global__ __launch_bounds__(256)
void gemm_bf16_k(const unsigned short* __restrict__ A, const int* __restrict__ rowIdx,
                 const unsigned short* __restrict__ Bt, const float* __restrict__ bias,
                 const float* __restrict__ addC, float* __restrict__ C,
                 unsigned short* __restrict__ Cb,
                 int M, int K, int Nc, int doRelu)
{
    __shared__ unsigned short Asl[128 * 32];
    __shared__ unsigned short Bsl[128 * 32];
    const int tid  = threadIdx.x;
    const int lane = tid & 63;
    const int wave = tid >> 6;
    const int wr = (wave >> 1) * 64;
    const int wc = (wave & 1) * 64;
    const int bm = blockIdx.y * 128;
    const int bn = blockIdx.x * 128;

    // staging: thread owns chunks c=tid and c=tid+256; row=c>>2 (0..127), slot=c&3
    const int row0 = tid >> 2;        // 0..63
    const int row1 = row0 + 64;       // 64..127
    const int slot = tid & 3;
    const int ss0 = slot ^ (row0 & 3) ^ ((row0 >> 2) & 3);
    const int ss1 = slot ^ (row1 & 3) ^ ((row1 >> 2) & 3);
    long aR0 = -1, aR1 = -1, bR0 = -1, bR1 = -1;
    {
        int g0 = bm + row0, g1 = bm + row1;
        if (g0 < M) aR0 = rowIdx ? (long)rowIdx[g0] : (long)g0;
        if (g1 < M) aR1 = rowIdx ? (long)rowIdx[g1] : (long)g1;
        if (bn + row0 < Nc) bR0 = bn + row0;
        if (bn + row1 < Nc) bR1 = bn + row1;
    }

    f32x4 acc[4][4] = {};
    const int rbase = lane & 15;
    const int ks = lane >> 4;

    for (int k0 = 0; k0 < K; k0 += 32) {
        uint4 z4 = make_uint4(0u, 0u, 0u, 0u);
        uint4 a0 = z4, a1 = z4, b0 = z4, b1 = z4;
        const long koff = k0 + slot * 8;
        if (aR0 >= 0) a0 = *reinterpret_cast<const uint4*>(A + aR0 * K + koff);
        if (aR1 >= 0) a1 = *reinterpret_cast<const uint4*>(A + aR1 * K + koff);
        if (bR0 >= 0) b0 = *reinterpret_cast<const uint4*>(Bt + bR0 * K + koff);
        if (bR1 >= 0) b1 = *reinterpret_cast<const uint4*>(Bt + bR1 * K + koff);
        *reinterpret_cast<uint4*>(&Asl[row0 * 32 + ss0 * 8]) = a0;
        *reinterpret_cast<uint4*>(&Asl[row1 * 32 + ss1 * 8]) = a1;
        *reinterpret_cast<uint4*>(&Bsl[row0 * 32 + ss0 * 8]) = b0;
        *reinterpret_cast<uint4*>(&Bsl[row1 * 32 + ss1 * 8]) = b1;
        __syncthreads();

        bf16x8 af[4], bfr[4];
        #pragma unroll
        for (int mi = 0; mi < 4; ++mi) {
            int r = wr + mi * 16 + rbase;
            int s = ks ^ (r & 3) ^ ((r >> 2) & 3);
            af[mi] = *reinterpret_cast<const bf16x8*>(&Asl[r * 32 + s * 8]);
        }
        #pragma unroll
        for (int ni = 0; ni < 4; ++ni) {
            int r = wc + ni * 16 + rbase;
            int s = ks ^ (r & 3) ^ ((r >> 2) & 3);
            bfr[ni] = *reinterpret_cast<const bf16x8*>(&Bsl[r * 32 + s * 8]);
        }
        #pragma unroll
        for (int mi = 0; mi < 4; ++mi)
            #pragma unroll
            for (int ni = 0; ni < 4; ++ni)
                acc[mi][ni] = __builtin_amdgcn_mfma_f32_16x16x32_bf16(
                    af[mi], bfr[ni], acc[mi][ni], 0, 0, 0);
        __syncthreads();
    }

    const int colBase = bn + wc + rbase;
    const int rowBase = bm + wr + ks * 4;
    #pragma unroll
    for (int mi = 0; mi < 4; ++mi) {
        #pragma unroll
        for (int j = 0; j < 4; ++j) {
            int r = rowBase + mi * 16 + j;
            if (r >= M) continue;
            long ro = (long)r * Nc;
            #pragma unroll
            for (int ni = 0; ni < 4; ++ni) {
                int cc = colBase + ni * 16;
                if (cc >= Nc) continue;
                float v = acc[mi][ni][j];
                if (bias)  v += bias[cc];
                if (doRelu) v = fmaxf(v, 0.0f);
                if (addC)  v += addC[ro + cc];
                if (Cb) Cb[ro + cc] = f2b(v);
                else    C[ro + cc] = v;
            }
        }
    }
}

// ---------------- LayerNorm (one wave per row) ----------------
// out(f32) [+ outb bf16] [+ scatter out2b[idx2[row]] bf16]
static __global__ __launch_bounds__(64)
void ln_k(const float* __restrict__ in, const float* __restrict__ g,
          const float* __restrict__ b, float* __restrict__ out, int Dw,
          unsigned short* __restrict__ outb,
          unsigned short* __restrict__ out2b, const int* __restrict__ idx2)
{
    const int row = blockIdx.x;
    const int lane = threadIdx.x;
    const int per = Dw >> 6;
    float v[8];
    const float* rp = in + (long)row * Dw;
    float s = 0.f;
    for (int i = 0; i < per; ++i) { v[i] = rp[i * 64 + lane]; s += v[i]; }
    #pragma unroll
    for (int off = 32; off; off >>= 1) s += __shfl_xor(s, off, 64);
    const float mu = s / (float)Dw;
    float var = 0.f;
    for (int i = 0; i < per; ++i) { float d = v[i] - mu; var += d * d; }
    #pragma unroll
    for (int off = 32; off; off >>= 1) var += __shfl_xor(var, off, 64);
    const float rstd = rsqrtf(var / (float)Dw + 1e-5f);
    for (int i = 0; i < per; ++i) {
        int c = i * 64 + lane;
        float o = (v[i] - mu) * rstd * g[c] + b[c];
        out[(long)row * Dw + c] = o;
        if (outb)  outb[(long)row * Dw + c] = f2b(o);
        if (out2b) out2b[(long)idx2[row] * Dw + c] = f2b(o);
    }
}

// ---------------- node-level edge attention ----------------
static __global__ __launch_bounds__(256)
void node_attn_k(const float* __restrict__ q, const float* __restrict__ k,
                 const float* __restrict__ v, const unsigned short* __restrict__ lgb,
                 const int* __restrict__ gsrc, const int* __restrict__ gdst,
                 float* __restrict__ wv, float* __restrict__ z)
{
    int e = blockIdx.x * 4 + (threadIdx.x >> 6);
    if (e >= NE) return;
    int lane = threadIdx.x & 63;
    int s = gsrc[e], d = gdst[e];
    float ed = b2f(lgb[(long)e * ED + lane]);
    const float* kp = k + (long)s * DD;
    const float* qp = q + (long)d * DD;
    const float* vp = v + (long)s * DD;
    float* wvp = wv + (long)d * DD;
    #pragma unroll
    for (int h = 0; h < NH; ++h) {
        float ks = kp[h * 64 + lane] + ed;
        float p = ks * qp[h * 64 + lane];
        #pragma unroll
        for (int off = 32; off; off >>= 1) p += __shfl_xor(p, off, 64);
        float sc = p * 0.125f;
        sc = fminf(fmaxf(sc, -10.0f), 10.0f);
        float w = expf(sc);
        atomicAdd(&wvp[h * 64 + lane], w * (vp[h * 64 + lane] + ed));
        if (lane == 0) atomicAdd(&z[(long)d * NH + h], w);
    }
}

// o_bf16 = wv / max(z,eps)
static __global__ __launch_bounds__(256)
void div_node_k(const float* __restrict__ wv, const float* __restrict__ z,
                unsigned short* __restrict__ ob) {
    int i = blockIdx.x * 256 + threadIdx.x;
    if (i >= NN * DD) return;
    int node = i >> 9;
    int h = (i >> 6) & 7;
    ob[i] = f2b(wv[i] / fmaxf(z[node * NH + h], 1e-9f));
}

// ---------------- line-graph attention ----------------
static __global__ __launch_bounds__(256)
void lg_attn_k(const float* __restrict__ qe, const float* __restrict__ ke,
               const float* __restrict__ ve, const int* __restrict__ lsrc,
               const int* __restrict__ ldst, float* __restrict__ wve,
               float* __restrict__ ze)
{
    int m = blockIdx.x * 4 + (threadIdx.x >> 6);
    if (m >= NLG) return;
    int lane = threadIdx.x & 63;
    int s = lsrc[m], d = ldst[m];
    float p = ke[(long)s * ED + lane] * qe[(long)d * ED + lane];
    p += __shfl_xor(p, 1, 64);
    p += __shfl_xor(p, 2, 64);
    p += __shfl_xor(p, 4, 64);
    float sc = p * 0.35355339059327373f;
    sc = fminf(fmaxf(sc, -10.0f), 10.0f);
    float w = expf(sc);
    atomicAdd(&wve[(long)d * ED + lane], w * ve[(long)s * ED + lane]);
    if ((lane & 7) == 0) atomicAdd(&ze[(long)d * NEH + (lane >> 3)], w);
}

static __global__ __launch_bounds__(256)
void div_edge_k(const float* __restrict__ wve, const float* __restrict__ ze,
                unsigned short* __restrict__ ob) {
    int i = blockIdx.x * 256 + threadIdx.x;
    if (i >= NEL * ED) return;
    int e = i >> 6;
    int h = (i >> 3) & 7;
    ob[i] = f2b(wve[i] / fmaxf(ze[e * NEH + h], 1e-9f));
}

// ---------------- host ----------------
static inline void run_gemm(hipStream_t st, const unsigned short* A, const int* idx,
                            const unsigned short* Bt, const float* bias,
                            const float* addC, float* C, unsigned short* Cb,
                            int M, int K, int Nc, int relu)
{
    dim3 g((Nc + 127) / 128, (M + 127) / 128);
    gemm_bf16_k<<<g, 256, 0, st>>>(A, idx, Bt, bias, addC, C, Cb, M, K, Nc, relu);
}

extern "C" void kernel_launch(void* const* d_in, const int* in_sizes, int n_in,
                              void* d_out, int out_size, void* d_ws, size_t ws_size,
                              hipStream_t stream)
{
    const float* x_in  = (const float*)d_in[0];
    const float* rel   = (const float*)d_in[1];
    const float* Wq    = (const float*)d_in[2];
    const float* bq    = (const float*)d_in[3];
    const float* Wk    = (const float*)d_in[4];
    const float* Wv    = (const float*)d_in[5];
    const float* Wo    = (const float*)d_in[6];
    const float* bo    = (const float*)d_in[7];
    const float* ln1g  = (const float*)d_in[8];
    const float* ln1b  = (const float*)d_in[9];
    const float* F1    = (const float*)d_in[10];
    const float* f1b   = (const float*)d_in[11];
    const float* F2    = (const float*)d_in[12];
    const float* f2b_  = (const float*)d_in[13];
    const float* ln2g  = (const float*)d_in[14];
    const float* ln2b  = (const float*)d_in[15];
    const float* Eq    = (const float*)d_in[16];
    const float* eqb   = (const float*)d_in[17];
    const float* Ek    = (const float*)d_in[18];
    const float* Ev    = (const float*)d_in[19];
    const float* Eo    = (const float*)d_in[20];
    const float* eob   = (const float*)d_in[21];
    const float* Ns    = (const float*)d_in[22];
    const float* nsb   = (const float*)d_in[23];
    const float* Nd    = (const float*)d_in[24];
    const float* ndb   = (const float*)d_in[25];
    const float* eln1g = (const float*)d_in[26];
    const float* eln1b = (const float*)d_in[27];
    const float* G1    = (const float*)d_in[28];
    const float* g1b   = (const float*)d_in[29];
    const float* G2    = (const float*)d_in[30];
    const float* g2b   = (const float*)d_in[31];
    const float* eln2g = (const float*)d_in[32];
    const float* eln2b = (const float*)d_in[33];
    const int* edge_feat   = (const int*)d_in[34];
    const int* local_index = (const int*)d_in[35];
    const int* src_ids     = (const int*)d_in[36];
    const int* dst_ids     = (const int*)d_in[37];
    const int* g_src       = (const int*)d_in[38];
    const int* g_dst       = (const int*)d_in[39];
    const int* lg_src      = (const int*)d_in[40];
    const int* lg_dst      = (const int*)d_in[41];

    // outputs live in d_out
    float* xbuf = (float*)d_out;                   // (NN, DD)
    float* el   = xbuf + (size_t)NN * DD;          // (NEL, ED)

    // ---- workspace: fp32 region then bf16 region (~195 MB total) ----
    float* W = (float*)d_ws;
    size_t off = 0;
    auto alloc = [&](size_t n) { float* p = W + off; off += (n + 63) & ~(size_t)63; return p; };
    float* t0 = alloc((size_t)NN * DD);    // q -> h
    float* t1 = alloc((size_t)NN * DD);    // k -> me -> qe
    float* t2 = alloc((size_t)NN * DD);    // v -> ke -> he
    float* t3 = alloc((size_t)NN * DD);    // wv -> ve -> edge out_pre
    float* e4 = alloc((size_t)NEL * ED);   // wve
    float* zb = alloc((size_t)NN * NH);
    float* ze = alloc((size_t)NEL * NEH);

    unsigned short* bp = (unsigned short*)(W + off);
    size_t boff = 0;
    auto balloc = [&](size_t n) { unsigned short* p = bp + boff; boff += (n + 63) & ~(size_t)63; return p; };
    unsigned short* lgb = balloc((size_t)NE * ED);
    unsigned short* xb  = balloc((size_t)NN * DD);
    unsigned short* hb  = balloc((size_t)NN * DD);   // o_bf16, then h_bf16
    unsigned short* elb = balloc((size_t)NEL * ED);
    unsigned short* e1b = balloc((size_t)NEL * ED);  // oe bf16
    unsigned short* heb = balloc((size_t)NEL * ED);
    unsigned short* fgb = balloc((size_t)2500 * 4 * DD);  // 5.12M: FFN chunk buf (node & edge)
    // transposed bf16 weights
    unsigned short* WqT = balloc((size_t)NL * DD * DD);
    unsigned short* WkT = balloc((size_t)NL * DD * DD);
    unsigned short* WvT = balloc((size_t)NL * DD * DD);
    unsigned short* WoT = balloc((size_t)NL * DD * DD);
    unsigned short* F1T = balloc((size_t)NL * DD * 4 * DD);
    unsigned short* F2T = balloc((size_t)NL * 4 * DD * DD);
    unsigned short* NsT = balloc((size_t)NL * DD * ED);
    unsigned short* NdT = balloc((size_t)NL * DD * ED);
    unsigned short* EqT = balloc((size_t)NL * ED * ED);
    unsigned short* EkT = balloc((size_t)NL * ED * ED);
    unsigned short* EvT = balloc((size_t)NL * ED * ED);
    unsigned short* EoT = balloc((size_t)NL * ED * ED);
    unsigned short* G1T = balloc((size_t)NL * ED * 4 * ED);
    unsigned short* G2T = balloc((size_t)NL * 4 * ED * ED);

    auto tc = [&](const float* src, unsigned short* dst, int K, int N) {
        int tot = NL * K * N;
        tcast_k<<<(tot + 255) / 256, 256, 0, stream>>>(src, dst, K, N, NL);
    };
    tc(Wq, WqT, DD, DD); tc(Wk, WkT, DD, DD); tc(Wv, WvT, DD, DD); tc(Wo, WoT, DD, DD);
    tc(F1, F1T, DD, 4 * DD); tc(F2, F2T, 4 * DD, DD);
    tc(Ns, NsT, DD, ED); tc(Nd, NdT, DD, ED);
    tc(Eq, EqT, ED, ED); tc(Ek, EkT, ED, ED); tc(Ev, EvT, ED, ED); tc(Eo, EoT, ED, ED);
    tc(G1, G1T, ED, 4 * ED); tc(G2, G2T, 4 * ED, ED);

    const int ndD = NN * DD;
    const int elD = NEL * ED;
    castcopy_k<<<(ndD + 255) / 256, 256, 0, stream>>>(x_in, xbuf, xb, ndD);
    init_lg_k<<<(NE * ED + 255) / 256, 256, 0, stream>>>(rel, edge_feat, lgb);
    gather64_k<<<(elD + 255) / 256, 256, 0, stream>>>(lgb, local_index, el, elb);

    for (int i = 0; i < NL; ++i) {
        size_t oD2 = (size_t)i * DD * DD, oE2 = (size_t)i * ED * ED;
        size_t oDE = (size_t)i * DD * ED;

        // ---- node attention (reads lgb BEFORE this layer's edge update) ----
        run_gemm(stream, xb, nullptr, WqT + oD2, bq + (size_t)i * DD, nullptr, t0, nullptr, NN, DD, DD, 0);
        run_gemm(stream, xb, nullptr, WkT + oD2, nullptr, nullptr, t1, nullptr, NN, DD, DD, 0);
        run_gemm(stream, xb, nullptr, WvT + oD2, nullptr, nullptr, t2, nullptr, NN, DD, DD, 0);
        zero_k<<<(ndD + 255) / 256, 256, 0, stream>>>(t3, ndD);
        zero_k<<<(NN * NH + 255) / 256, 256, 0, stream>>>(zb, NN * NH);
        node_attn_k<<<NE / 4, 256, 0, stream>>>(t0, t1, t2, lgb, g_src, g_dst, t3, zb);
        div_node_k<<<(ndD + 255) / 256, 256, 0, stream>>>(t3, zb, hb);   // o -> bf16 (hb slot)
        // h = LN(x_in + o @ Wo + bo)
        run_gemm(stream, hb, nullptr, WoT + oD2, bo + (size_t)i * DD, xbuf, t0, nullptr, NN, DD, DD, 0);
        ln_k<<<NN, 64, 0, stream>>>(t0, ln1g + (size_t)i * DD, ln1b + (size_t)i * DD, t0, DD, hb, nullptr, nullptr);

        // ---- edge branch (reads xb = bf16 of x_in; elb/lgb old values) ----
        run_gemm(stream, xb, dst_ids, NdT + oDE, ndb + (size_t)i * ED, nullptr, t1, nullptr, NEL, DD, ED, 0); // me
        run_gemm(stream, elb, nullptr, EkT + oE2, nullptr, t1, t2, nullptr, NEL, ED, ED, 0);                  // ke
        run_gemm(stream, elb, nullptr, EvT + oE2, nullptr, t1, t3, nullptr, NEL, ED, ED, 0);                  // ve
        run_gemm(stream, xb, src_ids, NsT + oDE, nsb + (size_t)i * ED, nullptr, t1, nullptr, NEL, DD, ED, 0); // qe pre
        run_gemm(stream, elb, nullptr, EqT + oE2, eqb + (size_t)i * ED, t1, t1, nullptr, NEL, ED, ED, 0);     // qe
        zero_k<<<(elD + 255) / 256, 256, 0, stream>>>(e4, elD);
        zero_k<<<(NEL * NEH + 255) / 256, 256, 0, stream>>>(ze, NEL * NEH);
        lg_attn_k<<<NLG / 4, 256, 0, stream>>>(t1, t2, t3, lg_src, lg_dst, e4, ze);
        div_edge_k<<<(elD + 255) / 256, 256, 0, stream>>>(e4, ze, e1b);
        // he = LN(el + oe @ Eo + eob)
        run_gemm(stream, e1b, nullptr, EoT + oE2, eob + (size_t)i * ED, el, t2, nullptr, NEL, ED, ED, 0);
        ln_k<<<NEL, 64, 0, stream>>>(t2, eln1g + (size_t)i * ED, eln1b + (size_t)i * ED, t2, ED, heb, nullptr, nullptr);
        // edge FFN, 3 chunks of 20000 rows
        for (int c = 0; c < 3; ++c) {
            size_t ro = (size_t)c * 20000;
            run_gemm(stream, heb + ro * ED, nullptr, G1T + (size_t)i * ED * 4 * ED,
                     g1b + (size_t)i * 4 * ED, nullptr, nullptr, fgb, 20000, ED, 4 * ED, 1);
            run_gemm(stream, fgb, nullptr, G2T + (size_t)i * 4 * ED * ED,
                     g2b + (size_t)i * ED, t2 + ro * ED, t3 + ro * ED, nullptr, 20000, 4 * ED, ED, 0);
        }
        // out_local = LN(...) -> el (f32) + elb (bf16) + scatter lgb[local_index]
        ln_k<<<NEL, 64, 0, stream>>>(t3, eln2g + (size_t)i * ED, eln2b + (size_t)i * ED, el, ED, elb, lgb, local_index);

        // ---- node FFN (x_in dead; write x in place), 4 chunks of 2500 rows ----
        for (int c = 0; c < 4; ++c) {
            size_t ro = (size_t)c * 2500;
            run_gemm(stream, hb + ro * DD, nullptr, F1T + (size_t)i * DD * 4 * DD,
                     f1b + (size_t)i * 4 * DD, nullptr, nullptr, fgb, 2500, DD, 4 * DD, 1);
            run_gemm(stream, fgb, nullptr, F2T + (size_t)i * 4 * DD * DD,
                     f2b_ + (size_t)i * DD, t0 + ro * DD, xbuf + ro * DD, nullptr, 2500, 4 * DD, DD, 0);
        }
        ln_k<<<NN, 64, 0, stream>>>(xbuf, ln2g + (size_t)i * DD, ln2b + (size_t)i * DD, xbuf, DD, xb, nullptr, nullptr);
    }
    // outputs already in d_out
}

// Round 4
// 4419.754 us; speedup vs baseline: 1.8088x; 1.2662x over previous
//
#include <hip/hip_runtime.h>
#include <math.h>

#define NN   10000      // nodes
#define DD   512        // node dim
#define NH   8          // node heads (DK=64)
#define NE   120000     // edges (global)
#define NEL  60000      // local edges
#define NLG  600000     // line-graph edges
#define ED   64         // edge dim (EH=8, EDK=8)
#define NEH  8
#define NL   4          // layers

typedef __attribute__((ext_vector_type(8))) short bf16x8;
typedef __attribute__((ext_vector_type(8))) unsigned short u16x8;
typedef __attribute__((ext_vector_type(4))) float f32x4;

__device__ __forceinline__ unsigned short f2b(float f) {
    union { float f; unsigned u; } c; c.f = f;
    unsigned u = c.u;
    unsigned r = u + 0x7FFFu + ((u >> 16) & 1u);
    return (unsigned short)(r >> 16);
}
__device__ __forceinline__ float b2f(unsigned short b) {
    union { unsigned u; float f; } c; c.u = ((unsigned)b) << 16;
    return c.f;
}

// ---------------- elementwise helpers ----------------
static __global__ __launch_bounds__(256)
void zero_k(float* __restrict__ p, int n) {
    int i = blockIdx.x * 256 + threadIdx.x;
    if (i < n) p[i] = 0.0f;
}

static __global__ __launch_bounds__(256)
void castcopy_k(const float* __restrict__ s, float* __restrict__ d,
                unsigned short* __restrict__ db, int n) {
    int i = blockIdx.x * 256 + threadIdx.x;
    if (i < n) { float v = s[i]; if (d) d[i] = v; db[i] = f2b(v); }
}

static __global__ __launch_bounds__(256)
void init_lg_k(const float* __restrict__ rel, const int* __restrict__ ef,
               unsigned short* __restrict__ lgb) {
    int i = blockIdx.x * 256 + threadIdx.x;
    if (i >= NE * ED) return;
    int e = i >> 6, c = i & 63;
    lgb[i] = f2b(rel[ef[e] * ED + c]);
}

static __global__ __launch_bounds__(256)
void gather64_k(const unsigned short* __restrict__ lgb, const int* __restrict__ idx,
                float* __restrict__ el, unsigned short* __restrict__ elb) {
    int i = blockIdx.x * 256 + threadIdx.x;
    if (i >= NEL * ED) return;
    int r = i >> 6;
    unsigned short b = lgb[(long)idx[r] * ED + (i & 63)];
    el[i] = b2f(b); elb[i] = b;
}

// weight transpose+cast: in[l][K][N] f32 -> out[l][N][K] bf16
static __global__ __launch_bounds__(256)
void tcast_k(const float* __restrict__ in, unsigned short* __restrict__ out,
             int K, int N, int Ln) {
    int i = blockIdx.x * 256 + threadIdx.x;
    int per = K * N;
    if (i >= Ln * per) return;
    int l = i / per, r = i - l * per;
    int n = r / K, k = r - n * K;
    out[i] = f2b(in[(long)l * per + (long)k * N + n]);
}

// ---------------- CSR build ----------------
static __global__ __launch_bounds__(256)
void hist_k(const int* __restrict__ dst, int* __restrict__ cnt, int n) {
    int i = blockIdx.x * 256 + threadIdx.x;
    if (i < n) atomicAdd(&cnt[dst[i]], 1);
}

// single-block exclusive scan; writes off and cur
static __global__ __launch_bounds__(1024)
void scan_k(const int* __restrict__ cnt, int* __restrict__ off,
            int* __restrict__ cur, int n) {
    __shared__ int part[1024];
    const int t = threadIdx.x;
    const int chunk = (n + 1023) >> 10;
    int lo = t * chunk, hi = lo + chunk; if (hi > n) hi = n; if (lo > n) lo = n;
    int s = 0;
    for (int i = lo; i < hi; ++i) s += cnt[i];
    part[t] = s;
    __syncthreads();
    for (int d = 1; d < 1024; d <<= 1) {
        int v = (t >= d) ? part[t - d] : 0;
        __syncthreads();
        part[t] += v;
        __syncthreads();
    }
    int run = (t == 0) ? 0 : part[t - 1];
    for (int i = lo; i < hi; ++i) { off[i] = run; cur[i] = run; run += cnt[i]; }
}

static __global__ __launch_bounds__(256)
void scatter_k(const int* __restrict__ dst, int* __restrict__ cur,
               int* __restrict__ ord, int n) {
    int i = blockIdx.x * 256 + threadIdx.x;
    if (i < n) { int p = atomicAdd(&cur[dst[i]], 1); ord[p] = i; }
}

// ---------------- bf16 MFMA GEMM ----------------
// C[M,Nc] = A[M,K]bf16 (opt row-gather) @ Bt[Nc,K]bf16^T  (+bias)(relu)(+addC)
// out: C fp32 OR Cb bf16. Tile 128x128, BK=32, 256 thr = 4 waves (2x2 of 64x64).
static __global__ __launch_bounds__(256)
void gemm_bf16_k(const unsigned short* __restrict__ A, const int* __restrict__ rowIdx,
                 const unsigned short* __restrict__ Bt, const float* __restrict__ bias,
                 const float* __restrict__ addC, float* __restrict__ C,
                 unsigned short* __restrict__ Cb,
                 int M, int K, int Nc, int doRelu)
{
    __shared__ unsigned short Asl[128 * 32];
    __shared__ unsigned short Bsl[128 * 32];
    const int tid  = threadIdx.x;
    const int lane = tid & 63;
    const int wave = tid >> 6;
    const int wr = (wave >> 1) * 64;
    const int wc = (wave & 1) * 64;
    const int bm = blockIdx.y * 128;
    const int bn = blockIdx.x * 128;

    const int row0 = tid >> 2;
    const int row1 = row0 + 64;
    const int slot = tid & 3;
    const int ss0 = slot ^ (row0 & 3) ^ ((row0 >> 2) & 3);
    const int ss1 = slot ^ (row1 & 3) ^ ((row1 >> 2) & 3);
    long aR0 = -1, aR1 = -1, bR0 = -1, bR1 = -1;
    {
        int g0 = bm + row0, g1 = bm + row1;
        if (g0 < M) aR0 = rowIdx ? (long)rowIdx[g0] : (long)g0;
        if (g1 < M) aR1 = rowIdx ? (long)rowIdx[g1] : (long)g1;
        if (bn + row0 < Nc) bR0 = bn + row0;
        if (bn + row1 < Nc) bR1 = bn + row1;
    }

    f32x4 acc[4][4] = {};
    const int rbase = lane & 15;
    const int ks = lane >> 4;

    for (int k0 = 0; k0 < K; k0 += 32) {
        uint4 z4 = make_uint4(0u, 0u, 0u, 0u);
        uint4 a0 = z4, a1 = z4, b0 = z4, b1 = z4;
        const long koff = k0 + slot * 8;
        if (aR0 >= 0) a0 = *reinterpret_cast<const uint4*>(A + aR0 * K + koff);
        if (aR1 >= 0) a1 = *reinterpret_cast<const uint4*>(A + aR1 * K + koff);
        if (bR0 >= 0) b0 = *reinterpret_cast<const uint4*>(Bt + bR0 * K + koff);
        if (bR1 >= 0) b1 = *reinterpret_cast<const uint4*>(Bt + bR1 * K + koff);
        *reinterpret_cast<uint4*>(&Asl[row0 * 32 + ss0 * 8]) = a0;
        *reinterpret_cast<uint4*>(&Asl[row1 * 32 + ss1 * 8]) = a1;
        *reinterpret_cast<uint4*>(&Bsl[row0 * 32 + ss0 * 8]) = b0;
        *reinterpret_cast<uint4*>(&Bsl[row1 * 32 + ss1 * 8]) = b1;
        __syncthreads();

        bf16x8 af[4], bfr[4];
        #pragma unroll
        for (int mi = 0; mi < 4; ++mi) {
            int r = wr + mi * 16 + rbase;
            int s = ks ^ (r & 3) ^ ((r >> 2) & 3);
            af[mi] = *reinterpret_cast<const bf16x8*>(&Asl[r * 32 + s * 8]);
        }
        #pragma unroll
        for (int ni = 0; ni < 4; ++ni) {
            int r = wc + ni * 16 + rbase;
            int s = ks ^ (r & 3) ^ ((r >> 2) & 3);
            bfr[ni] = *reinterpret_cast<const bf16x8*>(&Bsl[r * 32 + s * 8]);
        }
        #pragma unroll
        for (int mi = 0; mi < 4; ++mi)
            #pragma unroll
            for (int ni = 0; ni < 4; ++ni)
                acc[mi][ni] = __builtin_amdgcn_mfma_f32_16x16x32_bf16(
                    af[mi], bfr[ni], acc[mi][ni], 0, 0, 0);
        __syncthreads();
    }

    const int colBase = bn + wc + rbase;
    const int rowBase = bm + wr + ks * 4;
    #pragma unroll
    for (int mi = 0; mi < 4; ++mi) {
        #pragma unroll
        for (int j = 0; j < 4; ++j) {
            int r = rowBase + mi * 16 + j;
            if (r >= M) continue;
            long ro = (long)r * Nc;
            #pragma unroll
            for (int ni = 0; ni < 4; ++ni) {
                int cc = colBase + ni * 16;
                if (cc >= Nc) continue;
                float v = acc[mi][ni][j];
                if (bias)  v += bias[cc];
                if (doRelu) v = fmaxf(v, 0.0f);
                if (addC)  v += addC[ro + cc];
                if (Cb) Cb[ro + cc] = f2b(v);
                else    C[ro + cc] = v;
            }
        }
    }
}

// ---------------- LayerNorm (one wave per row) ----------------
static __global__ __launch_bounds__(64)
void ln_k(const float* __restrict__ in, const float* __restrict__ g,
          const float* __restrict__ b, float* __restrict__ out, int Dw,
          unsigned short* __restrict__ outb,
          unsigned short* __restrict__ out2b, const int* __restrict__ idx2)
{
    const int row = blockIdx.x;
    const int lane = threadIdx.x;
    const int per = Dw >> 6;
    float v[8];
    const float* rp = in + (long)row * Dw;
    float s = 0.f;
    for (int i = 0; i < per; ++i) { v[i] = rp[i * 64 + lane]; s += v[i]; }
    #pragma unroll
    for (int off = 32; off; off >>= 1) s += __shfl_xor(s, off, 64);
    const float mu = s / (float)Dw;
    float var = 0.f;
    for (int i = 0; i < per; ++i) { float d = v[i] - mu; var += d * d; }
    #pragma unroll
    for (int off = 32; off; off >>= 1) var += __shfl_xor(var, off, 64);
    const float rstd = rsqrtf(var / (float)Dw + 1e-5f);
    for (int i = 0; i < per; ++i) {
        int c = i * 64 + lane;
        float o = (v[i] - mu) * rstd * g[c] + b[c];
        out[(long)row * Dw + c] = o;
        if (outb)  outb[(long)row * Dw + c] = f2b(o);
        if (out2b) out2b[(long)idx2[row] * Dw + c] = f2b(o);
    }
}

// ---------------- node attention, CSR (one wave per dst node) ----------------
// lane = h*8+d8; each lane owns dims lane*8..lane*8+7 of the 512-dim row.
// Reads bf16 q/k/v/lg; writes o (bf16) into ob (may alias qb: each wave reads
// only its own q row before writing its own o row).
static __global__ __launch_bounds__(256)
void node_attn_csr_k(const unsigned short* __restrict__ qb,
                     const unsigned short* __restrict__ kb,
                     const unsigned short* __restrict__ vb,
                     const unsigned short* __restrict__ lgb,
                     const int* __restrict__ goff, const int* __restrict__ gord,
                     const int* __restrict__ gsrc,
                     unsigned short* __restrict__ ob)
{
    int node = blockIdx.x * 4 + (threadIdx.x >> 6);
    if (node >= NN) return;
    const int lane = threadIdx.x & 63;
    float qv[8];
    {
        u16x8 q8 = *reinterpret_cast<const u16x8*>(qb + (long)node * DD + lane * 8);
        #pragma unroll
        for (int i = 0; i < 8; ++i) qv[i] = b2f(q8[i]);
    }
    float wva[8] = {0.f, 0.f, 0.f, 0.f, 0.f, 0.f, 0.f, 0.f};
    float zac = 0.f;
    const int lo = goff[node];
    const int hi = (node + 1 < NN) ? goff[node + 1] : NE;
    for (int j = lo; j < hi; ++j) {
        int e = gord[j];
        int s = gsrc[e];
        u16x8 k8 = *reinterpret_cast<const u16x8*>(kb + (long)s * DD + lane * 8);
        u16x8 v8 = *reinterpret_cast<const u16x8*>(vb + (long)s * DD + lane * 8);
        u16x8 e8 = *reinterpret_cast<const u16x8*>(lgb + (long)e * ED + (lane & 7) * 8);
        float ed[8], vv[8];
        float p = 0.f;
        #pragma unroll
        for (int i = 0; i < 8; ++i) {
            ed[i] = b2f(e8[i]); vv[i] = b2f(v8[i]);
            p = fmaf(b2f(k8[i]) + ed[i], qv[i], p);
        }
        p += __shfl_xor(p, 1, 64);
        p += __shfl_xor(p, 2, 64);
        p += __shfl_xor(p, 4, 64);
        float sc = fminf(fmaxf(p * 0.125f, -10.0f), 10.0f);
        float w = expf(sc);
        #pragma unroll
        for (int i = 0; i < 8; ++i) wva[i] = fmaf(w, vv[i] + ed[i], wva[i]);
        zac += w;
    }
    const float inv = 1.0f / fmaxf(zac, 1e-9f);
    u16x8 o8;
    #pragma unroll
    for (int i = 0; i < 8; ++i) o8[i] = f2b(wva[i] * inv);
    *reinterpret_cast<u16x8*>(ob + (long)node * DD + lane * 8) = o8;
}

// ---------------- line-graph attention, CSR (one wave per dst local edge) ---
// lane = dim (64); 8-lane groups per head.
static __global__ __launch_bounds__(256)
void lg_attn_csr_k(const unsigned short* __restrict__ qeb,
                   const unsigned short* __restrict__ keb,
                   const unsigned short* __restrict__ veb,
                   const int* __restrict__ eoff, const int* __restrict__ eord,
                   const int* __restrict__ lsrc,
                   unsigned short* __restrict__ oeb)
{
    int d = blockIdx.x * 4 + (threadIdx.x >> 6);
    if (d >= NEL) return;
    const int lane = threadIdx.x & 63;
    const float qv = b2f(qeb[(long)d * ED + lane]);
    float oa = 0.f, zac = 0.f;
    const int lo = eoff[d];
    const int hi = (d + 1 < NEL) ? eoff[d + 1] : NLG;
    for (int j = lo; j < hi; ++j) {
        int m = eord[j];
        int s = lsrc[m];
        float kv = b2f(keb[(long)s * ED + lane]);
        float vv = b2f(veb[(long)s * ED + lane]);
        float p = kv * qv;
        p += __shfl_xor(p, 1, 64);
        p += __shfl_xor(p, 2, 64);
        p += __shfl_xor(p, 4, 64);
        float sc = fminf(fmaxf(p * 0.35355339059327373f, -10.0f), 10.0f);
        float w = expf(sc);
        oa = fmaf(w, vv, oa);
        zac += w;
    }
    oeb[(long)d * ED + lane] = f2b(oa / fmaxf(zac, 1e-9f));
}

// ---------------- host ----------------
static inline void run_gemm(hipStream_t st, const unsigned short* A, const int* idx,
                            const unsigned short* Bt, const float* bias,
                            const float* addC, float* C, unsigned short* Cb,
                            int M, int K, int Nc, int relu)
{
    dim3 g((Nc + 127) / 128, (M + 127) / 128);
    gemm_bf16_k<<<g, 256, 0, st>>>(A, idx, Bt, bias, addC, C, Cb, M, K, Nc, relu);
}

extern "C" void kernel_launch(void* const* d_in, const int* in_sizes, int n_in,
                              void* d_out, int out_size, void* d_ws, size_t ws_size,
                              hipStream_t stream)
{
    const float* x_in  = (const float*)d_in[0];
    const float* rel   = (const float*)d_in[1];
    const float* Wq    = (const float*)d_in[2];
    const float* bq    = (const float*)d_in[3];
    const float* Wk    = (const float*)d_in[4];
    const float* Wv    = (const float*)d_in[5];
    const float* Wo    = (const float*)d_in[6];
    const float* bo    = (const float*)d_in[7];
    const float* ln1g  = (const float*)d_in[8];
    const float* ln1b  = (const float*)d_in[9];
    const float* F1    = (const float*)d_in[10];
    const float* f1b   = (const float*)d_in[11];
    const float* F2    = (const float*)d_in[12];
    const float* f2b_  = (const float*)d_in[13];
    const float* ln2g  = (const float*)d_in[14];
    const float* ln2b  = (const float*)d_in[15];
    const float* Eq    = (const float*)d_in[16];
    const float* eqb   = (const float*)d_in[17];
    const float* Ek    = (const float*)d_in[18];
    const float* Ev    = (const float*)d_in[19];
    const float* Eo    = (const float*)d_in[20];
    const float* eob   = (const float*)d_in[21];
    const float* Ns    = (const float*)d_in[22];
    const float* nsb   = (const float*)d_in[23];
    const float* Nd    = (const float*)d_in[24];
    const float* ndb   = (const float*)d_in[25];
    const float* eln1g = (const float*)d_in[26];
    const float* eln1b = (const float*)d_in[27];
    const float* G1    = (const float*)d_in[28];
    const float* g1b   = (const float*)d_in[29];
    const float* G2    = (const float*)d_in[30];
    const float* g2b   = (const float*)d_in[31];
    const float* eln2g = (const float*)d_in[32];
    const float* eln2b = (const float*)d_in[33];
    const int* edge_feat   = (const int*)d_in[34];
    const int* local_index = (const int*)d_in[35];
    const int* src_ids     = (const int*)d_in[36];
    const int* dst_ids     = (const int*)d_in[37];
    const int* g_src       = (const int*)d_in[38];
    const int* g_dst       = (const int*)d_in[39];
    const int* lg_src      = (const int*)d_in[40];
    const int* lg_dst      = (const int*)d_in[41];

    // outputs live in d_out
    float* xbuf = (float*)d_out;                   // (NN, DD)
    float* el   = xbuf + (size_t)NN * DD;          // (NEL, ED)

    // ---- workspace layout (~210 MB) ----
    float* W = (float*)d_ws;
    size_t off = 0;
    auto alloc = [&](size_t n) { float* p = W + off; off += (n + 63) & ~(size_t)63; return p; };
    float* t0 = alloc((size_t)NN * DD);    // h pre-LN / FFN residual
    float* t1 = alloc((size_t)NN * DD);    // me / sns (fp32); aliased as FFN bf16 buf
    float* t2 = alloc((size_t)NEL * ED);   // he
    float* t3 = alloc((size_t)NEL * ED);   // edge FFN out pre-LN

    unsigned short* fgb = (unsigned short*)t1;   // FFN intermediate (bf16), alias of t1

    unsigned short* bp = (unsigned short*)(W + off);
    size_t boff = 0;
    auto balloc = [&](size_t n) { unsigned short* p = bp + boff; boff += (n + 63) & ~(size_t)63; return p; };
    unsigned short* lgb = balloc((size_t)NE * ED);
    unsigned short* xb  = balloc((size_t)NN * DD);
    unsigned short* qb  = balloc((size_t)NN * DD);   // q -> o -> keb
    unsigned short* kb  = balloc((size_t)NN * DD);   // k -> hb
    unsigned short* vb  = balloc((size_t)NN * DD);   // v -> veb
    unsigned short* elb = balloc((size_t)NEL * ED);
    unsigned short* e1b = balloc((size_t)NEL * ED);  // oe
    unsigned short* heb = balloc((size_t)NEL * ED);
    unsigned short* qeb = balloc((size_t)NEL * ED);
    unsigned short* hb  = kb;                        // h bf16 (k dead after attn)
    unsigned short* keb = qb;                        // ke bf16 (o dead after Wo gemm)
    unsigned short* veb = vb;                        // ve bf16 (v dead after attn)
    // transposed bf16 weights
    unsigned short* WqT = balloc((size_t)NL * DD * DD);
    unsigned short* WkT = balloc((size_t)NL * DD * DD);
    unsigned short* WvT = balloc((size_t)NL * DD * DD);
    unsigned short* WoT = balloc((size_t)NL * DD * DD);
    unsigned short* F1T = balloc((size_t)NL * DD * 4 * DD);
    unsigned short* F2T = balloc((size_t)NL * 4 * DD * DD);
    unsigned short* NsT = balloc((size_t)NL * DD * ED);
    unsigned short* NdT = balloc((size_t)NL * DD * ED);
    unsigned short* EqT = balloc((size_t)NL * ED * ED);
    unsigned short* EkT = balloc((size_t)NL * ED * ED);
    unsigned short* EvT = balloc((size_t)NL * ED * ED);
    unsigned short* EoT = balloc((size_t)NL * ED * ED);
    unsigned short* G1T = balloc((size_t)NL * ED * 4 * ED);
    unsigned short* G2T = balloc((size_t)NL * 4 * ED * ED);
    // CSR (ints)
    int* ip = (int*)(bp + ((boff + 63) & ~(size_t)63));
    size_t ioff = 0;
    auto ialloc = [&](size_t n) { int* p = ip + ioff; ioff += (n + 63) & ~(size_t)63; return p; };
    int* gcnt = ialloc(NN);
    int* goff = ialloc(NN);
    int* gcur = ialloc(NN);
    int* gord = ialloc(NE);
    int* ecnt = ialloc(NEL);
    int* eoff = ialloc(NEL);
    int* ecur = ialloc(NEL);
    int* eord = ialloc(NLG);

    auto tc = [&](const float* src, unsigned short* dst, int K, int N) {
        int tot = NL * K * N;
        tcast_k<<<(tot + 255) / 256, 256, 0, stream>>>(src, dst, K, N, NL);
    };
    tc(Wq, WqT, DD, DD); tc(Wk, WkT, DD, DD); tc(Wv, WvT, DD, DD); tc(Wo, WoT, DD, DD);
    tc(F1, F1T, DD, 4 * DD); tc(F2, F2T, 4 * DD, DD);
    tc(Ns, NsT, DD, ED); tc(Nd, NdT, DD, ED);
    tc(Eq, EqT, ED, ED); tc(Ek, EkT, ED, ED); tc(Ev, EvT, ED, ED); tc(Eo, EoT, ED, ED);
    tc(G1, G1T, ED, 4 * ED); tc(G2, G2T, 4 * ED, ED);

    // CSR build (once per launch)
    zero_k<<<(NN + 255) / 256, 256, 0, stream>>>((float*)gcnt, NN);
    hist_k<<<(NE + 255) / 256, 256, 0, stream>>>(g_dst, gcnt, NE);
    scan_k<<<1, 1024, 0, stream>>>(gcnt, goff, gcur, NN);
    scatter_k<<<(NE + 255) / 256, 256, 0, stream>>>(g_dst, gcur, gord, NE);
    zero_k<<<(NEL + 255) / 256, 256, 0, stream>>>((float*)ecnt, NEL);
    hist_k<<<(NLG + 255) / 256, 256, 0, stream>>>(lg_dst, ecnt, NLG);
    scan_k<<<1, 1024, 0, stream>>>(ecnt, eoff, ecur, NEL);
    scatter_k<<<(NLG + 255) / 256, 256, 0, stream>>>(lg_dst, ecur, eord, NLG);

    const int ndD = NN * DD;
    const int elD = NEL * ED;
    castcopy_k<<<(ndD + 255) / 256, 256, 0, stream>>>(x_in, xbuf, xb, ndD);
    init_lg_k<<<(NE * ED + 255) / 256, 256, 0, stream>>>(rel, edge_feat, lgb);
    gather64_k<<<(elD + 255) / 256, 256, 0, stream>>>(lgb, local_index, el, elb);

    for (int i = 0; i < NL; ++i) {
        size_t oD2 = (size_t)i * DD * DD, oE2 = (size_t)i * ED * ED;
        size_t oDE = (size_t)i * DD * ED;

        // ---- node attention (reads lgb BEFORE this layer's edge update) ----
        run_gemm(stream, xb, nullptr, WqT + oD2, bq + (size_t)i * DD, nullptr, nullptr, qb, NN, DD, DD, 0);
        run_gemm(stream, xb, nullptr, WkT + oD2, nullptr, nullptr, nullptr, kb, NN, DD, DD, 0);
        run_gemm(stream, xb, nullptr, WvT + oD2, nullptr, nullptr, nullptr, vb, NN, DD, DD, 0);
        node_attn_csr_k<<<NN / 4, 256, 0, stream>>>(qb, kb, vb, lgb, goff, gord, g_src, qb);
        // h = LN(x_in + o @ Wo + bo)
        run_gemm(stream, qb, nullptr, WoT + oD2, bo + (size_t)i * DD, xbuf, t0, nullptr, NN, DD, DD, 0);
        ln_k<<<NN, 64, 0, stream>>>(t0, ln1g + (size_t)i * DD, ln1b + (size_t)i * DD, t0, DD, hb, nullptr, nullptr);

        // ---- edge branch (reads xb = bf16 of x_in; elb/lgb old values) ----
        run_gemm(stream, xb, dst_ids, NdT + oDE, ndb + (size_t)i * ED, nullptr, t1, nullptr, NEL, DD, ED, 0); // me
        run_gemm(stream, elb, nullptr, EkT + oE2, nullptr, t1, nullptr, keb, NEL, ED, ED, 0);                 // ke+me
        run_gemm(stream, elb, nullptr, EvT + oE2, nullptr, t1, nullptr, veb, NEL, ED, ED, 0);                 // ve+me
        run_gemm(stream, xb, src_ids, NsT + oDE, nsb + (size_t)i * ED, nullptr, t1, nullptr, NEL, DD, ED, 0); // sns
        run_gemm(stream, elb, nullptr, EqT + oE2, eqb + (size_t)i * ED, t1, nullptr, qeb, NEL, ED, ED, 0);    // qe
        lg_attn_csr_k<<<NEL / 4, 256, 0, stream>>>(qeb, keb, veb, eoff, eord, lg_src, e1b);
        // he = LN(el + oe @ Eo + eob)
        run_gemm(stream, e1b, nullptr, EoT + oE2, eob + (size_t)i * ED, el, t2, nullptr, NEL, ED, ED, 0);
        ln_k<<<NEL, 64, 0, stream>>>(t2, eln1g + (size_t)i * ED, eln1b + (size_t)i * ED, t2, ED, heb, nullptr, nullptr);
        // edge FFN, 2 chunks of 30000 rows (fgb = t1 alias, 30000*256 shorts fit)
        for (int c = 0; c < 2; ++c) {
            size_t ro = (size_t)c * 30000;
            run_gemm(stream, heb + ro * ED, nullptr, G1T + (size_t)i * ED * 4 * ED,
                     g1b + (size_t)i * 4 * ED, nullptr, nullptr, fgb, 30000, ED, 4 * ED, 1);
            run_gemm(stream, fgb, nullptr, G2T + (size_t)i * 4 * ED * ED,
                     g2b + (size_t)i * ED, t2 + ro * ED, t3 + ro * ED, nullptr, 30000, 4 * ED, ED, 0);
        }
        // out_local = LN(...) -> el (f32) + elb (bf16) + scatter lgb[local_index]
        ln_k<<<NEL, 64, 0, stream>>>(t3, eln2g + (size_t)i * ED, eln2b + (size_t)i * ED, el, ED, elb, lgb, local_index);

        // ---- node FFN (x_in dead; write x in place), 4 chunks of 2500 rows ----
        for (int c = 0; c < 4; ++c) {
            size_t ro = (size_t)c * 2500;
            run_gemm(stream, hb + ro * DD, nullptr, F1T + (size_t)i * DD * 4 * DD,
                     f1b + (size_t)i * 4 * DD, nullptr, nullptr, fgb, 2500, DD, 4 * DD, 1);
            run_gemm(stream, fgb, nullptr, F2T + (size_t)i * 4 * DD * DD,
                     f2b_ + (size_t)i * DD, t0 + ro * DD, xbuf + ro * DD, nullptr, 2500, 4 * DD, DD, 0);
        }
        ln_k<<<NN, 64, 0, stream>>>(xbuf, ln2g + (size_t)i * DD, ln2b + (size_t)i * DD, xbuf, DD, xb, nullptr, nullptr);
    }
    // outputs already in d_out
}

// Round 5
// 3364.653 us; speedup vs baseline: 2.3761x; 1.3136x over previous
//
#include <hip/hip_runtime.h>
#include <math.h>

#define NN   10000      // nodes
#define DD   512        // node dim
#define NH   8          // node heads (DK=64)
#define NE   120000     // edges (global)
#define NEL  60000      // local edges
#define NLG  600000     // line-graph edges
#define ED   64         // edge dim (EH=8, EDK=8)
#define NEH  8
#define NL   4          // layers
#define QKVW 1536       // fused q|k|v row width

typedef __attribute__((ext_vector_type(8))) short bf16x8;
typedef __attribute__((ext_vector_type(8))) unsigned short u16x8;
typedef __attribute__((ext_vector_type(4))) float f32x4;

__device__ __forceinline__ unsigned short f2b(float f) {
    union { float f; unsigned u; } c; c.f = f;
    unsigned u = c.u;
    unsigned r = u + 0x7FFFu + ((u >> 16) & 1u);
    return (unsigned short)(r >> 16);
}
__device__ __forceinline__ float b2f(unsigned short b) {
    union { unsigned u; float f; } c; c.u = ((unsigned)b) << 16;
    return c.f;
}

// ---------------- elementwise helpers ----------------
static __global__ __launch_bounds__(256)
void zero_k(float* __restrict__ p, int n) {
    int i = blockIdx.x * 256 + threadIdx.x;
    if (i < n) p[i] = 0.0f;
}

static __global__ __launch_bounds__(256)
void castcopy_k(const float* __restrict__ s, float* __restrict__ d,
                unsigned short* __restrict__ db, int n) {
    int i = blockIdx.x * 256 + threadIdx.x;
    if (i < n) { float v = s[i]; if (d) d[i] = v; db[i] = f2b(v); }
}

static __global__ __launch_bounds__(256)
void init_lg_k(const float* __restrict__ rel, const int* __restrict__ ef,
               unsigned short* __restrict__ lgb) {
    int i = blockIdx.x * 256 + threadIdx.x;
    if (i >= NE * ED) return;
    int e = i >> 6, c = i & 63;
    lgb[i] = f2b(rel[ef[e] * ED + c]);
}

static __global__ __launch_bounds__(256)
void gather64_k(const unsigned short* __restrict__ lgb, const int* __restrict__ idx,
                float* __restrict__ el, unsigned short* __restrict__ elb) {
    int i = blockIdx.x * 256 + threadIdx.x;
    if (i >= NEL * ED) return;
    int r = i >> 6;
    unsigned short b = lgb[(long)idx[r] * ED + (i & 63)];
    el[i] = b2f(b); elb[i] = b;
}

// weight transpose+cast: in[l][K][N] f32 -> out[l][N][K] bf16
static __global__ __launch_bounds__(256)
void tcast_k(const float* __restrict__ in, unsigned short* __restrict__ out,
             int K, int N, int Ln) {
    int i = blockIdx.x * 256 + threadIdx.x;
    int per = K * N;
    if (i >= Ln * per) return;
    int l = i / per, r = i - l * per;
    int n = r / K, k = r - n * K;
    out[i] = f2b(in[(long)l * per + (long)k * N + n]);
}

// fused qkv weight: out[l][n=0..1535][k] from Wq/Wk/Wv [l][k][n&511]
static __global__ __launch_bounds__(256)
void build_qkvT_k(const float* __restrict__ Wq, const float* __restrict__ Wk,
                  const float* __restrict__ Wv, unsigned short* __restrict__ out) {
    int i = blockIdx.x * 256 + threadIdx.x;
    if (i >= NL * QKVW * DD) return;
    int l = i / (QKVW * DD), r = i - l * (QKVW * DD);
    int n = r / DD, k = r - n * DD;
    const float* src = (n < 512) ? Wq : (n < 1024) ? Wk : Wv;
    out[i] = f2b(src[(size_t)l * DD * DD + (size_t)k * DD + (n & 511)]);
}

static __global__ __launch_bounds__(256)
void build_qkvb_k(const float* __restrict__ bq, float* __restrict__ out) {
    int i = blockIdx.x * 256 + threadIdx.x;
    if (i >= NL * QKVW) return;
    int l = i / QKVW, c = i - l * QKVW;
    out[i] = (c < 512) ? bq[l * 512 + c] : 0.0f;
}

// ---------------- CSR build ----------------
static __global__ __launch_bounds__(256)
void hist_k(const int* __restrict__ dst, int* __restrict__ cnt, int n) {
    int i = blockIdx.x * 256 + threadIdx.x;
    if (i < n) atomicAdd(&cnt[dst[i]], 1);
}

// pass 1: per-block (256-wide) exclusive scan + block totals
static __global__ __launch_bounds__(256)
void scanA_k(const int* __restrict__ cnt, int* __restrict__ off,
             int* __restrict__ bsum, int n) {
    __shared__ int sm[256];
    const int t = threadIdx.x;
    const int i = blockIdx.x * 256 + t;
    int v = (i < n) ? cnt[i] : 0;
    sm[t] = v; __syncthreads();
    int x = v;
    #pragma unroll
    for (int d = 1; d < 256; d <<= 1) {
        int y = (t >= d) ? sm[t - d] : 0;
        __syncthreads();
        x += y; sm[t] = x; __syncthreads();
    }
    if (i < n) off[i] = x - v;
    if (t == 255) bsum[blockIdx.x] = x;
}

// pass 2: single block, exclusive scan of block totals (nb <= 1024)
static __global__ __launch_bounds__(1024)
void scanB_k(int* __restrict__ bsum, int nb) {
    __shared__ int sm[1024];
    const int t = threadIdx.x;
    int v = (t < nb) ? bsum[t] : 0;
    sm[t] = v; __syncthreads();
    int x = v;
    #pragma unroll
    for (int d = 1; d < 1024; d <<= 1) {
        int y = (t >= d) ? sm[t - d] : 0;
        __syncthreads();
        x += y; sm[t] = x; __syncthreads();
    }
    if (t < nb) bsum[t] = x - v;
}

// pass 3: add block offsets; write cur
static __global__ __launch_bounds__(256)
void scanC_k(const int* __restrict__ bsum, int* __restrict__ off,
             int* __restrict__ cur, int n) {
    int i = blockIdx.x * 256 + threadIdx.x;
    if (i < n) { int o = off[i] + bsum[blockIdx.x]; off[i] = o; cur[i] = o; }
}

static __global__ __launch_bounds__(256)
void scatter_k(const int* __restrict__ dst, int* __restrict__ cur,
               int* __restrict__ ord, int n) {
    int i = blockIdx.x * 256 + threadIdx.x;
    if (i < n) { int p = atomicAdd(&cur[dst[i]], 1); ord[p] = i; }
}

// ---------------- bf16 MFMA GEMM ----------------
// C[M,Nc] = A[M,K]bf16 (opt row-gather) @ Bt[Nc,K]bf16^T  (+bias)(relu)(+addC)
// out: C fp32 OR Cb bf16. Tile 128x128, BK=32, 256 thr = 4 waves (2x2 of 64x64).
static __global__ __launch_bounds__(256)
void gemm_bf16_k(const unsigned short* __restrict__ A, const int* __restrict__ rowIdx,
                 const unsigned short* __restrict__ Bt, const float* __restrict__ bias,
                 const float* __restrict__ addC, float* __restrict__ C,
                 unsigned short* __restrict__ Cb,
                 int M, int K, int Nc, int doRelu)
{
    __shared__ unsigned short Asl[128 * 32];
    __shared__ unsigned short Bsl[128 * 32];
    const int tid  = threadIdx.x;
    const int lane = tid & 63;
    const int wave = tid >> 6;
    const int wr = (wave >> 1) * 64;
    const int wc = (wave & 1) * 64;
    const int bm = blockIdx.y * 128;
    const int bn = blockIdx.x * 128;

    const int row0 = tid >> 2;
    const int row1 = row0 + 64;
    const int slot = tid & 3;
    const int ss0 = slot ^ (row0 & 3) ^ ((row0 >> 2) & 3);
    const int ss1 = slot ^ (row1 & 3) ^ ((row1 >> 2) & 3);
    long aR0 = -1, aR1 = -1, bR0 = -1, bR1 = -1;
    {
        int g0 = bm + row0, g1 = bm + row1;
        if (g0 < M) aR0 = rowIdx ? (long)rowIdx[g0] : (long)g0;
        if (g1 < M) aR1 = rowIdx ? (long)rowIdx[g1] : (long)g1;
        if (bn + row0 < Nc) bR0 = bn + row0;
        if (bn + row1 < Nc) bR1 = bn + row1;
    }

    f32x4 acc[4][4] = {};
    const int rbase = lane & 15;
    const int ks = lane >> 4;

    for (int k0 = 0; k0 < K; k0 += 32) {
        uint4 z4 = make_uint4(0u, 0u, 0u, 0u);
        uint4 a0 = z4, a1 = z4, b0 = z4, b1 = z4;
        const long koff = k0 + slot * 8;
        if (aR0 >= 0) a0 = *reinterpret_cast<const uint4*>(A + aR0 * K + koff);
        if (aR1 >= 0) a1 = *reinterpret_cast<const uint4*>(A + aR1 * K + koff);
        if (bR0 >= 0) b0 = *reinterpret_cast<const uint4*>(Bt + bR0 * K + koff);
        if (bR1 >= 0) b1 = *reinterpret_cast<const uint4*>(Bt + bR1 * K + koff);
        *reinterpret_cast<uint4*>(&Asl[row0 * 32 + ss0 * 8]) = a0;
        *reinterpret_cast<uint4*>(&Asl[row1 * 32 + ss1 * 8]) = a1;
        *reinterpret_cast<uint4*>(&Bsl[row0 * 32 + ss0 * 8]) = b0;
        *reinterpret_cast<uint4*>(&Bsl[row1 * 32 + ss1 * 8]) = b1;
        __syncthreads();

        bf16x8 af[4], bfr[4];
        #pragma unroll
        for (int mi = 0; mi < 4; ++mi) {
            int r = wr + mi * 16 + rbase;
            int s = ks ^ (r & 3) ^ ((r >> 2) & 3);
            af[mi] = *reinterpret_cast<const bf16x8*>(&Asl[r * 32 + s * 8]);
        }
        #pragma unroll
        for (int ni = 0; ni < 4; ++ni) {
            int r = wc + ni * 16 + rbase;
            int s = ks ^ (r & 3) ^ ((r >> 2) & 3);
            bfr[ni] = *reinterpret_cast<const bf16x8*>(&Bsl[r * 32 + s * 8]);
        }
        #pragma unroll
        for (int mi = 0; mi < 4; ++mi)
            #pragma unroll
            for (int ni = 0; ni < 4; ++ni)
                acc[mi][ni] = __builtin_amdgcn_mfma_f32_16x16x32_bf16(
                    af[mi], bfr[ni], acc[mi][ni], 0, 0, 0);
        __syncthreads();
    }

    const int colBase = bn + wc + rbase;
    const int rowBase = bm + wr + ks * 4;
    #pragma unroll
    for (int mi = 0; mi < 4; ++mi) {
        #pragma unroll
        for (int j = 0; j < 4; ++j) {
            int r = rowBase + mi * 16 + j;
            if (r >= M) continue;
            long ro = (long)r * Nc;
            #pragma unroll
            for (int ni = 0; ni < 4; ++ni) {
                int cc = colBase + ni * 16;
                if (cc >= Nc) continue;
                float v = acc[mi][ni][j];
                if (bias)  v += bias[cc];
                if (doRelu) v = fmaxf(v, 0.0f);
                if (addC)  v += addC[ro + cc];
                if (Cb) Cb[ro + cc] = f2b(v);
                else    C[ro + cc] = v;
            }
        }
    }
}

// ---------------- LayerNorm (one wave per row) ----------------
static __global__ __launch_bounds__(64)
void ln_k(const float* __restrict__ in, const float* __restrict__ g,
          const float* __restrict__ b, float* __restrict__ out, int Dw,
          unsigned short* __restrict__ outb,
          unsigned short* __restrict__ out2b, const int* __restrict__ idx2)
{
    const int row = blockIdx.x;
    const int lane = threadIdx.x;
    const int per = Dw >> 6;
    float v[8];
    const float* rp = in + (long)row * Dw;
    float s = 0.f;
    for (int i = 0; i < per; ++i) { v[i] = rp[i * 64 + lane]; s += v[i]; }
    #pragma unroll
    for (int off = 32; off; off >>= 1) s += __shfl_xor(s, off, 64);
    const float mu = s / (float)Dw;
    float var = 0.f;
    for (int i = 0; i < per; ++i) { float d = v[i] - mu; var += d * d; }
    #pragma unroll
    for (int off = 32; off; off >>= 1) var += __shfl_xor(var, off, 64);
    const float rstd = rsqrtf(var / (float)Dw + 1e-5f);
    for (int i = 0; i < per; ++i) {
        int c = i * 64 + lane;
        float o = (v[i] - mu) * rstd * g[c] + b[c];
        out[(long)row * Dw + c] = o;
        if (outb)  outb[(long)row * Dw + c] = f2b(o);
        if (out2b) out2b[(long)idx2[row] * Dw + c] = f2b(o);
    }
}

// ---------------- node attention, CSR (one wave per dst node) ----------------
// qkv interleaved [node][1536] = q|k|v. lane = h*8+d8 (owns 8 dims).
static __global__ __launch_bounds__(256)
void node_attn_csr_k(const unsigned short* __restrict__ qkv,
                     const unsigned short* __restrict__ lgb,
                     const int* __restrict__ goff, const int* __restrict__ gord,
                     const int* __restrict__ gsrc,
                     unsigned short* __restrict__ ob)
{
    int node = blockIdx.x * 4 + (threadIdx.x >> 6);
    if (node >= NN) return;
    const int lane = threadIdx.x & 63;
    float qv[8];
    {
        u16x8 q8 = *reinterpret_cast<const u16x8*>(qkv + (long)node * QKVW + lane * 8);
        #pragma unroll
        for (int i = 0; i < 8; ++i) qv[i] = b2f(q8[i]);
    }
    float wva[8] = {0.f, 0.f, 0.f, 0.f, 0.f, 0.f, 0.f, 0.f};
    float zac = 0.f;
    const int lo = goff[node];
    const int hi = (node + 1 < NN) ? goff[node + 1] : NE;
    for (int j = lo; j < hi; ++j) {
        int e = gord[j];
        int s = gsrc[e];
        u16x8 k8 = *reinterpret_cast<const u16x8*>(qkv + (long)s * QKVW + 512 + lane * 8);
        u16x8 v8 = *reinterpret_cast<const u16x8*>(qkv + (long)s * QKVW + 1024 + lane * 8);
        u16x8 e8 = *reinterpret_cast<const u16x8*>(lgb + (long)e * ED + (lane & 7) * 8);
        float ed[8], vv[8];
        float p = 0.f;
        #pragma unroll
        for (int i = 0; i < 8; ++i) {
            ed[i] = b2f(e8[i]); vv[i] = b2f(v8[i]);
            p = fmaf(b2f(k8[i]) + ed[i], qv[i], p);
        }
        p += __shfl_xor(p, 1, 64);
        p += __shfl_xor(p, 2, 64);
        p += __shfl_xor(p, 4, 64);
        float sc = fminf(fmaxf(p * 0.125f, -10.0f), 10.0f);
        float w = expf(sc);
        #pragma unroll
        for (int i = 0; i < 8; ++i) wva[i] = fmaf(w, vv[i] + ed[i], wva[i]);
        zac += w;
    }
    const float inv = 1.0f / fmaxf(zac, 1e-9f);
    u16x8 o8;
    #pragma unroll
    for (int i = 0; i < 8; ++i) o8[i] = f2b(wva[i] * inv);
    *reinterpret_cast<u16x8*>(ob + (long)node * DD + lane * 8) = o8;
}

// ---------------- line-graph attention, CSR (one wave per dst local edge) ---
static __global__ __launch_bounds__(256)
void lg_attn_csr_k(const unsigned short* __restrict__ qeb,
                   const unsigned short* __restrict__ keb,
                   const unsigned short* __restrict__ veb,
                   const int* __restrict__ eoff, const int* __restrict__ eord,
                   const int* __restrict__ lsrc,
                   unsigned short* __restrict__ oeb)
{
    int d = blockIdx.x * 4 + (threadIdx.x >> 6);
    if (d >= NEL) return;
    const int lane = threadIdx.x & 63;
    const float qv = b2f(qeb[(long)d * ED + lane]);
    float oa = 0.f, zac = 0.f;
    const int lo = eoff[d];
    const int hi = (d + 1 < NEL) ? eoff[d + 1] : NLG;
    for (int j = lo; j < hi; ++j) {
        int m = eord[j];
        int s = lsrc[m];
        float kv = b2f(keb[(long)s * ED + lane]);
        float vv = b2f(veb[(long)s * ED + lane]);
        float p = kv * qv;
        p += __shfl_xor(p, 1, 64);
        p += __shfl_xor(p, 2, 64);
        p += __shfl_xor(p, 4, 64);
        float sc = fminf(fmaxf(p * 0.35355339059327373f, -10.0f), 10.0f);
        float w = expf(sc);
        oa = fmaf(w, vv, oa);
        zac += w;
    }
    oeb[(long)d * ED + lane] = f2b(oa / fmaxf(zac, 1e-9f));
}

// ---------------- host ----------------
static inline void run_gemm(hipStream_t st, const unsigned short* A, const int* idx,
                            const unsigned short* Bt, const float* bias,
                            const float* addC, float* C, unsigned short* Cb,
                            int M, int K, int Nc, int relu)
{
    dim3 g((Nc + 127) / 128, (M + 127) / 128);
    gemm_bf16_k<<<g, 256, 0, st>>>(A, idx, Bt, bias, addC, C, Cb, M, K, Nc, relu);
}

extern "C" void kernel_launch(void* const* d_in, const int* in_sizes, int n_in,
                              void* d_out, int out_size, void* d_ws, size_t ws_size,
                              hipStream_t stream)
{
    const float* x_in  = (const float*)d_in[0];
    const float* rel   = (const float*)d_in[1];
    const float* Wq    = (const float*)d_in[2];
    const float* bq    = (const float*)d_in[3];
    const float* Wk    = (const float*)d_in[4];
    const float* Wv    = (const float*)d_in[5];
    const float* Wo    = (const float*)d_in[6];
    const float* bo    = (const float*)d_in[7];
    const float* ln1g  = (const float*)d_in[8];
    const float* ln1b  = (const float*)d_in[9];
    const float* F1    = (const float*)d_in[10];
    const float* f1b   = (const float*)d_in[11];
    const float* F2    = (const float*)d_in[12];
    const float* f2b_  = (const float*)d_in[13];
    const float* ln2g  = (const float*)d_in[14];
    const float* ln2b  = (const float*)d_in[15];
    const float* Eq    = (const float*)d_in[16];
    const float* eqb   = (const float*)d_in[17];
    const float* Ek    = (const float*)d_in[18];
    const float* Ev    = (const float*)d_in[19];
    const float* Eo    = (const float*)d_in[20];
    const float* eob   = (const float*)d_in[21];
    const float* Ns    = (const float*)d_in[22];
    const float* nsb   = (const float*)d_in[23];
    const float* Nd    = (const float*)d_in[24];
    const float* ndb   = (const float*)d_in[25];
    const float* eln1g = (const float*)d_in[26];
    const float* eln1b = (const float*)d_in[27];
    const float* G1    = (const float*)d_in[28];
    const float* g1b   = (const float*)d_in[29];
    const float* G2    = (const float*)d_in[30];
    const float* g2b   = (const float*)d_in[31];
    const float* eln2g = (const float*)d_in[32];
    const float* eln2b = (const float*)d_in[33];
    const int* edge_feat   = (const int*)d_in[34];
    const int* local_index = (const int*)d_in[35];
    const int* src_ids     = (const int*)d_in[36];
    const int* dst_ids     = (const int*)d_in[37];
    const int* g_src       = (const int*)d_in[38];
    const int* g_dst       = (const int*)d_in[39];
    const int* lg_src      = (const int*)d_in[40];
    const int* lg_dst      = (const int*)d_in[41];

    // outputs live in d_out
    float* xbuf = (float*)d_out;                   // (NN, DD)
    float* el   = xbuf + (size_t)NN * DD;          // (NEL, ED)

    // ---- workspace layout (~214 MB) ----
    float* W = (float*)d_ws;
    size_t off = 0;
    auto alloc = [&](size_t n) { float* p = W + off; off += (n + 63) & ~(size_t)63; return p; };
    float* t0 = alloc((size_t)NN * DD);     // h pre-LN
    float* t1 = alloc((size_t)NEL * ED);    // me / sns (fp32)
    float* t2 = alloc((size_t)NEL * ED);    // he pre-LN
    float* t3 = alloc((size_t)NEL * ED);    // edge FFN out pre-LN
    float* qkvb = alloc((size_t)NL * QKVW); // fused qkv bias

    unsigned short* bp = (unsigned short*)(W + off);
    size_t boff = 0;
    auto balloc = [&](size_t n) { unsigned short* p = bp + boff; boff += (n + 63) & ~(size_t)63; return p; };
    unsigned short* lgb = balloc((size_t)NE * ED);
    unsigned short* xb  = balloc((size_t)NN * DD);
    unsigned short* qkv = balloc((size_t)NN * QKVW);    // q|k|v interleaved
    unsigned short* elb = balloc((size_t)NEL * ED);
    unsigned short* e1b = balloc((size_t)NEL * ED);     // oe
    unsigned short* heb = balloc((size_t)NEL * ED);
    unsigned short* qeb = balloc((size_t)NEL * ED);
    unsigned short* fgb = balloc((size_t)NEL * 4 * ED); // 15.36M: FFN intermediate / o
    // aliases into the dead qkv region (after attention + Wo)
    unsigned short* hb  = qkv;                           // h bf16   (5.12M)
    unsigned short* keb = qkv + (size_t)NN * DD;         // ke bf16  (3.84M)
    unsigned short* veb = keb + (size_t)NEL * ED;        // ve bf16  (3.84M)
    unsigned short* ob  = fgb;                           // o bf16   (5.12M)
    // transposed bf16 weights
    unsigned short* WqkvT = balloc((size_t)NL * QKVW * DD);
    unsigned short* WoT = balloc((size_t)NL * DD * DD);
    unsigned short* F1T = balloc((size_t)NL * DD * 4 * DD);
    unsigned short* F2T = balloc((size_t)NL * 4 * DD * DD);
    unsigned short* NsT = balloc((size_t)NL * DD * ED);
    unsigned short* NdT = balloc((size_t)NL * DD * ED);
    unsigned short* EqT = balloc((size_t)NL * ED * ED);
    unsigned short* EkT = balloc((size_t)NL * ED * ED);
    unsigned short* EvT = balloc((size_t)NL * ED * ED);
    unsigned short* EoT = balloc((size_t)NL * ED * ED);
    unsigned short* G1T = balloc((size_t)NL * ED * 4 * ED);
    unsigned short* G2T = balloc((size_t)NL * 4 * ED * ED);
    // CSR (ints)
    int* ip = (int*)(bp + ((boff + 63) & ~(size_t)63));
    size_t ioff = 0;
    auto ialloc = [&](size_t n) { int* p = ip + ioff; ioff += (n + 63) & ~(size_t)63; return p; };
    int* gcnt = ialloc(NN);
    int* goff = ialloc(NN);
    int* gcur = ialloc(NN);
    int* gord = ialloc(NE);
    int* ecnt = ialloc(NEL);
    int* eoff = ialloc(NEL);
    int* ecur = ialloc(NEL);
    int* eord = ialloc(NLG);
    int* bsum = ialloc(1024);

    auto tc = [&](const float* src, unsigned short* dst, int K, int N) {
        int tot = NL * K * N;
        tcast_k<<<(tot + 255) / 256, 256, 0, stream>>>(src, dst, K, N, NL);
    };
    build_qkvT_k<<<(NL * QKVW * DD + 255) / 256, 256, 0, stream>>>(Wq, Wk, Wv, WqkvT);
    build_qkvb_k<<<(NL * QKVW + 255) / 256, 256, 0, stream>>>(bq, qkvb);
    tc(Wo, WoT, DD, DD);
    tc(F1, F1T, DD, 4 * DD); tc(F2, F2T, 4 * DD, DD);
    tc(Ns, NsT, DD, ED); tc(Nd, NdT, DD, ED);
    tc(Eq, EqT, ED, ED); tc(Ek, EkT, ED, ED); tc(Ev, EvT, ED, ED); tc(Eo, EoT, ED, ED);
    tc(G1, G1T, ED, 4 * ED); tc(G2, G2T, 4 * ED, ED);

    // CSR build (hierarchical scan)
    const int nbG = (NN + 255) / 256, nbE = (NEL + 255) / 256;
    zero_k<<<(NN + 255) / 256, 256, 0, stream>>>((float*)gcnt, NN);
    hist_k<<<(NE + 255) / 256, 256, 0, stream>>>(g_dst, gcnt, NE);
    scanA_k<<<nbG, 256, 0, stream>>>(gcnt, goff, bsum, NN);
    scanB_k<<<1, 1024, 0, stream>>>(bsum, nbG);
    scanC_k<<<nbG, 256, 0, stream>>>(bsum, goff, gcur, NN);
    scatter_k<<<(NE + 255) / 256, 256, 0, stream>>>(g_dst, gcur, gord, NE);
    zero_k<<<(NEL + 255) / 256, 256, 0, stream>>>((float*)ecnt, NEL);
    hist_k<<<(NLG + 255) / 256, 256, 0, stream>>>(lg_dst, ecnt, NLG);
    scanA_k<<<nbE, 256, 0, stream>>>(ecnt, eoff, bsum, NEL);
    scanB_k<<<1, 1024, 0, stream>>>(bsum, nbE);
    scanC_k<<<nbE, 256, 0, stream>>>(bsum, eoff, ecur, NEL);
    scatter_k<<<(NLG + 255) / 256, 256, 0, stream>>>(lg_dst, ecur, eord, NLG);

    const int ndD = NN * DD;
    const int elD = NEL * ED;
    castcopy_k<<<(ndD + 255) / 256, 256, 0, stream>>>(x_in, xbuf, xb, ndD);
    init_lg_k<<<(NE * ED + 255) / 256, 256, 0, stream>>>(rel, edge_feat, lgb);
    gather64_k<<<(elD + 255) / 256, 256, 0, stream>>>(lgb, local_index, el, elb);

    for (int i = 0; i < NL; ++i) {
        size_t oD2 = (size_t)i * DD * DD, oE2 = (size_t)i * ED * ED;
        size_t oDE = (size_t)i * DD * ED;

        // ---- node attention (reads lgb BEFORE this layer's edge update) ----
        run_gemm(stream, xb, nullptr, WqkvT + (size_t)i * QKVW * DD, qkvb + (size_t)i * QKVW,
                 nullptr, nullptr, qkv, NN, DD, QKVW, 0);
        node_attn_csr_k<<<NN / 4, 256, 0, stream>>>(qkv, lgb, goff, gord, g_src, ob);
        // h = LN(x_in + o @ Wo + bo)
        run_gemm(stream, ob, nullptr, WoT + oD2, bo + (size_t)i * DD, xbuf, t0, nullptr, NN, DD, DD, 0);
        ln_k<<<NN, 64, 0, stream>>>(t0, ln1g + (size_t)i * DD, ln1b + (size_t)i * DD, t0, DD, hb, nullptr, nullptr);

        // ---- edge branch (reads xb = bf16 of x_in; elb/lgb old values) ----
        run_gemm(stream, xb, dst_ids, NdT + oDE, ndb + (size_t)i * ED, nullptr, t1, nullptr, NEL, DD, ED, 0); // me
        run_gemm(stream, elb, nullptr, EkT + oE2, nullptr, t1, nullptr, keb, NEL, ED, ED, 0);                 // ke+me
        run_gemm(stream, elb, nullptr, EvT + oE2, nullptr, t1, nullptr, veb, NEL, ED, ED, 0);                 // ve+me
        run_gemm(stream, xb, src_ids, NsT + oDE, nsb + (size_t)i * ED, nullptr, t1, nullptr, NEL, DD, ED, 0); // sns
        run_gemm(stream, elb, nullptr, EqT + oE2, eqb + (size_t)i * ED, t1, nullptr, qeb, NEL, ED, ED, 0);    // qe
        lg_attn_csr_k<<<NEL / 4, 256, 0, stream>>>(qeb, keb, veb, eoff, eord, lg_src, e1b);
        // he = LN(el + oe @ Eo + eob)
        run_gemm(stream, e1b, nullptr, EoT + oE2, eob + (size_t)i * ED, el, t2, nullptr, NEL, ED, ED, 0);
        ln_k<<<NEL, 64, 0, stream>>>(t2, eln1g + (size_t)i * ED, eln1b + (size_t)i * ED, t2, ED, heb, nullptr, nullptr);
        // edge FFN, single chunk (fgb = 60000x256 bf16)
        run_gemm(stream, heb, nullptr, G1T + (size_t)i * ED * 4 * ED,
                 g1b + (size_t)i * 4 * ED, nullptr, nullptr, fgb, NEL, ED, 4 * ED, 1);
        run_gemm(stream, fgb, nullptr, G2T + (size_t)i * 4 * ED * ED,
                 g2b + (size_t)i * ED, t2, t3, nullptr, NEL, 4 * ED, ED, 0);
        // out_local = LN(...) -> el (f32) + elb (bf16) + scatter lgb[local_index]
        ln_k<<<NEL, 64, 0, stream>>>(t3, eln2g + (size_t)i * ED, eln2b + (size_t)i * ED, el, ED, elb, lgb, local_index);

        // ---- node FFN (2 chunks of 5000 rows; fgb holds 5000x2048 bf16) ----
        for (int c = 0; c < 2; ++c) {
            size_t ro = (size_t)c * 5000;
            run_gemm(stream, hb + ro * DD, nullptr, F1T + (size_t)i * DD * 4 * DD,
                     f1b + (size_t)i * 4 * DD, nullptr, nullptr, fgb, 5000, DD, 4 * DD, 1);
            run_gemm(stream, fgb, nullptr, F2T + (size_t)i * 4 * DD * DD,
                     f2b_ + (size_t)i * DD, t0 + ro * DD, xbuf + ro * DD, nullptr, 5000, 4 * DD, DD, 0);
        }
        ln_k<<<NN, 64, 0, stream>>>(xbuf, ln2g + (size_t)i * DD, ln2b + (size_t)i * DD, xbuf, DD, xb, nullptr, nullptr);
    }
    // outputs already in d_out
}

// Round 6
// 2533.861 us; speedup vs baseline: 3.1551x; 1.3279x over previous
//
#include <hip/hip_runtime.h>
#include <math.h>

#define NN   10000      // nodes
#define DD   512        // node dim
#define NH   8          // node heads (DK=64)
#define NE   120000     // edges (global)
#define NEL  60000      // local edges
#define NLG  600000     // line-graph edges
#define ED   64         // edge dim (EH=8, EDK=8)
#define NEH  8
#define NL   4          // layers
#define QKVW 1536       // fused q|k|v row width

typedef __attribute__((ext_vector_type(8))) short bf16x8;
typedef __attribute__((ext_vector_type(8))) unsigned short u16x8;
typedef __attribute__((ext_vector_type(4))) float f32x4;

__device__ __forceinline__ unsigned short f2b(float f) {
    union { float f; unsigned u; } c; c.f = f;
    unsigned u = c.u;
    unsigned r = u + 0x7FFFu + ((u >> 16) & 1u);
    return (unsigned short)(r >> 16);
}
__device__ __forceinline__ float b2f(unsigned short b) {
    union { unsigned u; float f; } c; c.u = ((unsigned)b) << 16;
    return c.f;
}

// ---------------- elementwise helpers ----------------
static __global__ __launch_bounds__(256)
void zero_k(float* __restrict__ p, int n) {
    int i = blockIdx.x * 256 + threadIdx.x;
    if (i < n) p[i] = 0.0f;
}

static __global__ __launch_bounds__(256)
void castcopy_k(const float* __restrict__ s, float* __restrict__ d,
                unsigned short* __restrict__ db, int n) {
    int i = blockIdx.x * 256 + threadIdx.x;
    if (i < n) { float v = s[i]; if (d) d[i] = v; db[i] = f2b(v); }
}

static __global__ __launch_bounds__(256)
void init_lg_k(const float* __restrict__ rel, const int* __restrict__ ef,
               unsigned short* __restrict__ lgb) {
    int i = blockIdx.x * 256 + threadIdx.x;
    if (i >= NE * ED) return;
    int e = i >> 6, c = i & 63;
    lgb[i] = f2b(rel[ef[e] * ED + c]);
}

static __global__ __launch_bounds__(256)
void gather64_k(const unsigned short* __restrict__ lgb, const int* __restrict__ idx,
                float* __restrict__ el, unsigned short* __restrict__ elb) {
    int i = blockIdx.x * 256 + threadIdx.x;
    if (i >= NEL * ED) return;
    int r = i >> 6;
    unsigned short b = lgb[(long)idx[r] * ED + (i & 63)];
    el[i] = b2f(b); elb[i] = b;
}

// ---------------- LDS-tiled transpose+cast ----------------
// in [l][K][N] f32 -> out[l*lstride + (rowOff+n)*rowStride + colOff + k] bf16
static __global__ __launch_bounds__(256)
void ttrans_k(const float* __restrict__ in, unsigned short* __restrict__ out,
              int K, int N, long lstride, int rowStride, int rowOff, int colOff) {
    __shared__ float sm[32][33];
    const int l = blockIdx.z;
    const int kt = blockIdx.x * 32, nt = blockIdx.y * 32;
    const int tx = threadIdx.x & 31, ty = threadIdx.x >> 5;   // ty 0..7
    const float* ip = in + (size_t)l * K * N;
    #pragma unroll
    for (int r = 0; r < 4; ++r)
        sm[ty + 8 * r][tx] = ip[(size_t)(kt + ty + 8 * r) * N + nt + tx];
    __syncthreads();
    unsigned short* op = out + (size_t)l * lstride;
    #pragma unroll
    for (int r = 0; r < 4; ++r) {
        int n = nt + ty + 8 * r;
        op[(size_t)(rowOff + n) * rowStride + colOff + kt + tx] = f2b(sm[tx][ty + 8 * r]);
    }
}

static __global__ __launch_bounds__(256)
void build_qkvb_k(const float* __restrict__ bq, float* __restrict__ out) {
    int i = blockIdx.x * 256 + threadIdx.x;
    if (i >= NL * QKVW) return;
    int l = i / QKVW, c = i - l * QKVW;
    out[i] = (c < 512) ? bq[l * 512 + c] : 0.0f;
}

// kvb[l*128+c] = ndb[l*64+(c&63)] ; qb2[l*64+c] = eqb+nsb
static __global__ __launch_bounds__(256)
void ebias_k(const float* __restrict__ ndb, const float* __restrict__ eqb,
             const float* __restrict__ nsb, float* __restrict__ kvb,
             float* __restrict__ qb2) {
    int i = blockIdx.x * 256 + threadIdx.x;
    if (i < NL * 128) kvb[i] = ndb[(i >> 7) * 64 + (i & 63)];
    if (i < NL * 64)  qb2[i] = eqb[i] + nsb[i];
}

// ---------------- CSR build ----------------
static __global__ __launch_bounds__(256)
void hist_k(const int* __restrict__ dst, int* __restrict__ cnt, int n) {
    int i = blockIdx.x * 256 + threadIdx.x;
    if (i < n) atomicAdd(&cnt[dst[i]], 1);
}

static __global__ __launch_bounds__(256)
void scanA_k(const int* __restrict__ cnt, int* __restrict__ off,
             int* __restrict__ bsum, int n) {
    __shared__ int sm[256];
    const int t = threadIdx.x;
    const int i = blockIdx.x * 256 + t;
    int v = (i < n) ? cnt[i] : 0;
    sm[t] = v; __syncthreads();
    int x = v;
    #pragma unroll
    for (int d = 1; d < 256; d <<= 1) {
        int y = (t >= d) ? sm[t - d] : 0;
        __syncthreads();
        x += y; sm[t] = x; __syncthreads();
    }
    if (i < n) off[i] = x - v;
    if (t == 255) bsum[blockIdx.x] = x;
}

static __global__ __launch_bounds__(1024)
void scanB_k(int* __restrict__ bsum, int nb) {
    __shared__ int sm[1024];
    const int t = threadIdx.x;
    int v = (t < nb) ? bsum[t] : 0;
    sm[t] = v; __syncthreads();
    int x = v;
    #pragma unroll
    for (int d = 1; d < 1024; d <<= 1) {
        int y = (t >= d) ? sm[t - d] : 0;
        __syncthreads();
        x += y; sm[t] = x; __syncthreads();
    }
    if (t < nb) bsum[t] = x - v;
}

static __global__ __launch_bounds__(256)
void scanC_k(const int* __restrict__ bsum, int* __restrict__ off,
             int* __restrict__ cur, int n) {
    int i = blockIdx.x * 256 + threadIdx.x;
    if (i < n) { int o = off[i] + bsum[blockIdx.x]; off[i] = o; cur[i] = o; }
}

static __global__ __launch_bounds__(256)
void scatter_k(const int* __restrict__ dst, int* __restrict__ cur,
               int* __restrict__ ord, int n) {
    int i = blockIdx.x * 256 + threadIdx.x;
    if (i < n) { int p = atomicAdd(&cur[dst[i]], 1); ord[p] = i; }
}

// flatten indirections: npack[j]=(e, gsrc[e]) ; esrc[j]=lsrc[eord[j]]
static __global__ __launch_bounds__(256)
void pack_k(const int* __restrict__ gord, const int* __restrict__ gsrc,
            const int* __restrict__ eord, const int* __restrict__ lsrc,
            int2* __restrict__ npack, int* __restrict__ esrc) {
    int i = blockIdx.x * 256 + threadIdx.x;
    if (i < NE) { int e = gord[i]; npack[i] = make_int2(e, gsrc[e]); }
    if (i < NLG) esrc[i] = lsrc[eord[i]];
}

// ---------------- bf16 MFMA GEMM (with optional split-K concat A) ----------
// If A2==null: C = A[M,K] @ Bt[Nc,K]^T.
// Else: A-row r = [ A[r][0:K1] | A2[idx2[r]][0:K-K1] ]  (A stride K1, A2 stride DD).
static __global__ __launch_bounds__(256)
void gemm_bf16_k(const unsigned short* __restrict__ A,
                 const unsigned short* __restrict__ A2, const int* __restrict__ idx2,
                 const unsigned short* __restrict__ Bt, const float* __restrict__ bias,
                 const float* __restrict__ addC, float* __restrict__ C,
                 unsigned short* __restrict__ Cb,
                 int M, int K, int Nc, int doRelu, int K1)
{
    __shared__ unsigned short Asl[128 * 32];
    __shared__ unsigned short Bsl[128 * 32];
    const int tid  = threadIdx.x;
    const int lane = tid & 63;
    const int wave = tid >> 6;
    const int wr = (wave >> 1) * 64;
    const int wc = (wave & 1) * 64;
    const int bm = blockIdx.y * 128;
    const int bn = blockIdx.x * 128;

    const int row0 = tid >> 2;
    const int row1 = row0 + 64;
    const int slot = tid & 3;
    const int ss0 = slot ^ (row0 & 3) ^ ((row0 >> 2) & 3);
    const int ss1 = slot ^ (row1 & 3) ^ ((row1 >> 2) & 3);
    const int g0 = bm + row0, g1 = bm + row1;
    const bool v0 = g0 < M, v1 = g1 < M;
    long iR0 = 0, iR1 = 0;
    if (A2) { if (v0) iR0 = idx2[g0]; if (v1) iR1 = idx2[g1]; }
    const bool bv0 = bn + row0 < Nc, bv1 = bn + row1 < Nc;

    f32x4 acc[4][4] = {};
    const int rbase = lane & 15;
    const int ks = lane >> 4;

    for (int k0 = 0; k0 < K; k0 += 32) {
        uint4 z4 = make_uint4(0u, 0u, 0u, 0u);
        uint4 a0 = z4, a1 = z4, b0 = z4, b1 = z4;
        const long koff = k0 + slot * 8;
        if (!A2) {
            if (v0) a0 = *reinterpret_cast<const uint4*>(A + (long)g0 * K + koff);
            if (v1) a1 = *reinterpret_cast<const uint4*>(A + (long)g1 * K + koff);
        } else if (k0 < K1) {
            if (v0) a0 = *reinterpret_cast<const uint4*>(A + (long)g0 * K1 + koff);
            if (v1) a1 = *reinterpret_cast<const uint4*>(A + (long)g1 * K1 + koff);
        } else {
            if (v0) a0 = *reinterpret_cast<const uint4*>(A2 + iR0 * DD + (koff - K1));
            if (v1) a1 = *reinterpret_cast<const uint4*>(A2 + iR1 * DD + (koff - K1));
        }
        if (bv0) b0 = *reinterpret_cast<const uint4*>(Bt + (long)(bn + row0) * K + koff);
        if (bv1) b1 = *reinterpret_cast<const uint4*>(Bt + (long)(bn + row1) * K + koff);
        *reinterpret_cast<uint4*>(&Asl[row0 * 32 + ss0 * 8]) = a0;
        *reinterpret_cast<uint4*>(&Asl[row1 * 32 + ss1 * 8]) = a1;
        *reinterpret_cast<uint4*>(&Bsl[row0 * 32 + ss0 * 8]) = b0;
        *reinterpret_cast<uint4*>(&Bsl[row1 * 32 + ss1 * 8]) = b1;
        __syncthreads();

        bf16x8 af[4], bfr[4];
        #pragma unroll
        for (int mi = 0; mi < 4; ++mi) {
            int r = wr + mi * 16 + rbase;
            int s = ks ^ (r & 3) ^ ((r >> 2) & 3);
            af[mi] = *reinterpret_cast<const bf16x8*>(&Asl[r * 32 + s * 8]);
        }
        #pragma unroll
        for (int ni = 0; ni < 4; ++ni) {
            int r = wc + ni * 16 + rbase;
            int s = ks ^ (r & 3) ^ ((r >> 2) & 3);
            bfr[ni] = *reinterpret_cast<const bf16x8*>(&Bsl[r * 32 + s * 8]);
        }
        #pragma unroll
        for (int mi = 0; mi < 4; ++mi)
            #pragma unroll
            for (int ni = 0; ni < 4; ++ni)
                acc[mi][ni] = __builtin_amdgcn_mfma_f32_16x16x32_bf16(
                    af[mi], bfr[ni], acc[mi][ni], 0, 0, 0);
        __syncthreads();
    }

    const int colBase = bn + wc + rbase;
    const int rowBase = bm + wr + ks * 4;
    #pragma unroll
    for (int mi = 0; mi < 4; ++mi) {
        #pragma unroll
        for (int j = 0; j < 4; ++j) {
            int r = rowBase + mi * 16 + j;
            if (r >= M) continue;
            long ro = (long)r * Nc;
            #pragma unroll
            for (int ni = 0; ni < 4; ++ni) {
                int cc = colBase + ni * 16;
                if (cc >= Nc) continue;
                float v = acc[mi][ni][j];
                if (bias)  v += bias[cc];
                if (doRelu) v = fmaxf(v, 0.0f);
                if (addC)  v += addC[ro + cc];
                if (Cb) Cb[ro + cc] = f2b(v);
                else    C[ro + cc] = v;
            }
        }
    }
}

// ---------------- LayerNorm (wave per row, 4 rows/block) ----------------
static __global__ __launch_bounds__(256)
void ln_k(const float* __restrict__ in, const float* __restrict__ g,
          const float* __restrict__ b, float* __restrict__ out, int Dw, int nrows,
          unsigned short* __restrict__ outb,
          unsigned short* __restrict__ out2b, const int* __restrict__ idx2)
{
    const int row = blockIdx.x * 4 + (threadIdx.x >> 6);
    if (row >= nrows) return;
    const int lane = threadIdx.x & 63;
    const int per = Dw >> 6;
    float v[8];
    const float* rp = in + (long)row * Dw;
    float s = 0.f;
    for (int i = 0; i < per; ++i) { v[i] = rp[i * 64 + lane]; s += v[i]; }
    #pragma unroll
    for (int off = 32; off; off >>= 1) s += __shfl_xor(s, off, 64);
    const float mu = s / (float)Dw;
    float var = 0.f;
    for (int i = 0; i < per; ++i) { float d = v[i] - mu; var += d * d; }
    #pragma unroll
    for (int off = 32; off; off >>= 1) var += __shfl_xor(var, off, 64);
    const float rstd = rsqrtf(var / (float)Dw + 1e-5f);
    for (int i = 0; i < per; ++i) {
        int c = i * 64 + lane;
        float o = (v[i] - mu) * rstd * g[c] + b[c];
        out[(long)row * Dw + c] = o;
        if (outb)  outb[(long)row * Dw + c] = f2b(o);
        if (out2b) out2b[(long)idx2[row] * Dw + c] = f2b(o);
    }
}

// ---------------- node attention, CSR, 2-way unrolled ----------------
static __global__ __launch_bounds__(256)
void node_attn_csr_k(const unsigned short* __restrict__ qkv,
                     const unsigned short* __restrict__ lgb,
                     const int* __restrict__ goff, const int2* __restrict__ npack,
                     unsigned short* __restrict__ ob)
{
    int node = blockIdx.x * 4 + (threadIdx.x >> 6);
    if (node >= NN) return;
    const int lane = threadIdx.x & 63;
    float qv[8];
    {
        u16x8 q8 = *reinterpret_cast<const u16x8*>(qkv + (long)node * QKVW + lane * 8);
        #pragma unroll
        for (int i = 0; i < 8; ++i) qv[i] = b2f(q8[i]);
    }
    float wva[8] = {0.f, 0.f, 0.f, 0.f, 0.f, 0.f, 0.f, 0.f};
    float zac = 0.f;
    int j = goff[node];
    const int hi = (node + 1 < NN) ? goff[node + 1] : NE;
    const int eoffl = (lane & 7) * 8;

    for (; j + 2 <= hi; j += 2) {
        int2 pa = npack[j], pb = npack[j + 1];
        u16x8 kA = *reinterpret_cast<const u16x8*>(qkv + (long)pa.y * QKVW + 512 + lane * 8);
        u16x8 vA = *reinterpret_cast<const u16x8*>(qkv + (long)pa.y * QKVW + 1024 + lane * 8);
        u16x8 eA = *reinterpret_cast<const u16x8*>(lgb + (long)pa.x * ED + eoffl);
        u16x8 kB = *reinterpret_cast<const u16x8*>(qkv + (long)pb.y * QKVW + 512 + lane * 8);
        u16x8 vB = *reinterpret_cast<const u16x8*>(qkv + (long)pb.y * QKVW + 1024 + lane * 8);
        u16x8 eB = *reinterpret_cast<const u16x8*>(lgb + (long)pb.x * ED + eoffl);
        float edA[8], vvA[8], edB[8], vvB[8];
        float pA = 0.f, pB = 0.f;
        #pragma unroll
        for (int i = 0; i < 8; ++i) {
            edA[i] = b2f(eA[i]); vvA[i] = b2f(vA[i]);
            pA = fmaf(b2f(kA[i]) + edA[i], qv[i], pA);
            edB[i] = b2f(eB[i]); vvB[i] = b2f(vB[i]);
            pB = fmaf(b2f(kB[i]) + edB[i], qv[i], pB);
        }
        pA += __shfl_xor(pA, 1, 64); pA += __shfl_xor(pA, 2, 64); pA += __shfl_xor(pA, 4, 64);
        pB += __shfl_xor(pB, 1, 64); pB += __shfl_xor(pB, 2, 64); pB += __shfl_xor(pB, 4, 64);
        float wA = expf(fminf(fmaxf(pA * 0.125f, -10.0f), 10.0f));
        float wB = expf(fminf(fmaxf(pB * 0.125f, -10.0f), 10.0f));
        #pragma unroll
        for (int i = 0; i < 8; ++i) {
            wva[i] = fmaf(wA, vvA[i] + edA[i], wva[i]);
            wva[i] = fmaf(wB, vvB[i] + edB[i], wva[i]);
        }
        zac += wA + wB;
    }
    for (; j < hi; ++j) {
        int2 pa = npack[j];
        u16x8 kA = *reinterpret_cast<const u16x8*>(qkv + (long)pa.y * QKVW + 512 + lane * 8);
        u16x8 vA = *reinterpret_cast<const u16x8*>(qkv + (long)pa.y * QKVW + 1024 + lane * 8);
        u16x8 eA = *reinterpret_cast<const u16x8*>(lgb + (long)pa.x * ED + eoffl);
        float edA[8], vvA[8];
        float pA = 0.f;
        #pragma unroll
        for (int i = 0; i < 8; ++i) {
            edA[i] = b2f(eA[i]); vvA[i] = b2f(vA[i]);
            pA = fmaf(b2f(kA[i]) + edA[i], qv[i], pA);
        }
        pA += __shfl_xor(pA, 1, 64); pA += __shfl_xor(pA, 2, 64); pA += __shfl_xor(pA, 4, 64);
        float wA = expf(fminf(fmaxf(pA * 0.125f, -10.0f), 10.0f));
        #pragma unroll
        for (int i = 0; i < 8; ++i) wva[i] = fmaf(wA, vvA[i] + edA[i], wva[i]);
        zac += wA;
    }
    const float inv = 1.0f / fmaxf(zac, 1e-9f);
    u16x8 o8;
    #pragma unroll
    for (int i = 0; i < 8; ++i) o8[i] = f2b(wva[i] * inv);
    *reinterpret_cast<u16x8*>(ob + (long)node * DD + lane * 8) = o8;
}

// ---------------- line-graph attention, CSR, 4-way unrolled ----------------
// keve interleaved rows [m][128] = ke|ve
static __global__ __launch_bounds__(256)
void lg_attn_csr_k(const unsigned short* __restrict__ qeb,
                   const unsigned short* __restrict__ keve,
                   const int* __restrict__ eoff, const int* __restrict__ esrc,
                   unsigned short* __restrict__ oeb)
{
    int d = blockIdx.x * 4 + (threadIdx.x >> 6);
    if (d >= NEL) return;
    const int lane = threadIdx.x & 63;
    const float qv = b2f(qeb[(long)d * ED + lane]);
    float oa = 0.f, zac = 0.f;
    int j = eoff[d];
    const int hi = (d + 1 < NEL) ? eoff[d + 1] : NLG;
    for (; j + 4 <= hi; j += 4) {
        int ss[4]; float kk[4], vv[4];
        #pragma unroll
        for (int u = 0; u < 4; ++u) ss[u] = esrc[j + u];
        #pragma unroll
        for (int u = 0; u < 4; ++u) {
            kk[u] = b2f(keve[(long)ss[u] * 128 + lane]);
            vv[u] = b2f(keve[(long)ss[u] * 128 + 64 + lane]);
        }
        #pragma unroll
        for (int u = 0; u < 4; ++u) {
            float p = kk[u] * qv;
            p += __shfl_xor(p, 1, 64); p += __shfl_xor(p, 2, 64); p += __shfl_xor(p, 4, 64);
            float w = expf(fminf(fmaxf(p * 0.35355339059327373f, -10.0f), 10.0f));
            oa = fmaf(w, vv[u], oa);
            zac += w;
        }
    }
    for (; j < hi; ++j) {
        int s = esrc[j];
        float kv = b2f(keve[(long)s * 128 + lane]);
        float vv = b2f(keve[(long)s * 128 + 64 + lane]);
        float p = kv * qv;
        p += __shfl_xor(p, 1, 64); p += __shfl_xor(p, 2, 64); p += __shfl_xor(p, 4, 64);
        float w = expf(fminf(fmaxf(p * 0.35355339059327373f, -10.0f), 10.0f));
        oa = fmaf(w, vv, oa);
        zac += w;
    }
    oeb[(long)d * ED + lane] = f2b(oa / fmaxf(zac, 1e-9f));
}

// ---------------- host ----------------
static inline void run_gemm(hipStream_t st, const unsigned short* A,
                            const unsigned short* Bt, const float* bias,
                            const float* addC, float* C, unsigned short* Cb,
                            int M, int K, int Nc, int relu)
{
    dim3 g((Nc + 127) / 128, (M + 127) / 128);
    gemm_bf16_k<<<g, 256, 0, st>>>(A, nullptr, nullptr, Bt, bias, addC, C, Cb, M, K, Nc, relu, 0);
}
static inline void run_gemm2(hipStream_t st, const unsigned short* A1,
                             const unsigned short* A2, const int* idx2,
                             const unsigned short* Bt, const float* bias,
                             unsigned short* Cb, int M, int K, int Nc, int K1)
{
    dim3 g((Nc + 127) / 128, (M + 127) / 128);
    gemm_bf16_k<<<g, 256, 0, st>>>(A1, A2, idx2, Bt, bias, nullptr, nullptr, Cb, M, K, Nc, 0, K1);
}

extern "C" void kernel_launch(void* const* d_in, const int* in_sizes, int n_in,
                              void* d_out, int out_size, void* d_ws, size_t ws_size,
                              hipStream_t stream)
{
    const float* x_in  = (const float*)d_in[0];
    const float* rel   = (const float*)d_in[1];
    const float* Wq    = (const float*)d_in[2];
    const float* bq    = (const float*)d_in[3];
    const float* Wk    = (const float*)d_in[4];
    const float* Wv    = (const float*)d_in[5];
    const float* Wo    = (const float*)d_in[6];
    const float* bo    = (const float*)d_in[7];
    const float* ln1g  = (const float*)d_in[8];
    const float* ln1b  = (const float*)d_in[9];
    const float* F1    = (const float*)d_in[10];
    const float* f1b   = (const float*)d_in[11];
    const float* F2    = (const float*)d_in[12];
    const float* f2b_  = (const float*)d_in[13];
    const float* ln2g  = (const float*)d_in[14];
    const float* ln2b  = (const float*)d_in[15];
    const float* Eq    = (const float*)d_in[16];
    const float* eqb   = (const float*)d_in[17];
    const float* Ek    = (const float*)d_in[18];
    const float* Ev    = (const float*)d_in[19];
    const float* Eo    = (const float*)d_in[20];
    const float* eob   = (const float*)d_in[21];
    const float* Ns    = (const float*)d_in[22];
    const float* nsb   = (const float*)d_in[23];
    const float* Nd    = (const float*)d_in[24];
    const float* ndb   = (const float*)d_in[25];
    const float* eln1g = (const float*)d_in[26];
    const float* eln1b = (const float*)d_in[27];
    const float* G1    = (const float*)d_in[28];
    const float* g1b   = (const float*)d_in[29];
    const float* G2    = (const float*)d_in[30];
    const float* g2b   = (const float*)d_in[31];
    const float* eln2g = (const float*)d_in[32];
    const float* eln2b = (const float*)d_in[33];
    const int* edge_feat   = (const int*)d_in[34];
    const int* local_index = (const int*)d_in[35];
    const int* src_ids     = (const int*)d_in[36];
    const int* dst_ids     = (const int*)d_in[37];
    const int* g_src       = (const int*)d_in[38];
    const int* g_dst       = (const int*)d_in[39];
    const int* lg_src      = (const int*)d_in[40];
    const int* lg_dst      = (const int*)d_in[41];

    // outputs live in d_out
    float* xbuf = (float*)d_out;                   // (NN, DD)
    float* el   = xbuf + (size_t)NN * DD;          // (NEL, ED)

    // ---- workspace layout (~214 MB) ----
    float* W = (float*)d_ws;
    size_t off = 0;
    auto alloc = [&](size_t n) { float* p = W + off; off += (n + 63) & ~(size_t)63; return p; };
    float* t0  = alloc((size_t)NN * DD);     // h pre-LN
    float* t2  = alloc((size_t)NEL * ED);    // he pre-LN
    float* t3  = alloc((size_t)NEL * ED);    // edge FFN out pre-LN
    float* qkvb = alloc((size_t)NL * QKVW);  // fused qkv bias
    float* kvb  = alloc((size_t)NL * 128);   // ke|ve bias
    float* qb2  = alloc((size_t)NL * ED);    // qe bias (eqb+nsb)

    unsigned short* bp = (unsigned short*)(W + off);
    size_t boff = 0;
    auto balloc = [&](size_t n) { unsigned short* p = bp + boff; boff += (n + 63) & ~(size_t)63; return p; };
    unsigned short* lgb = balloc((size_t)NE * ED);
    unsigned short* xb  = balloc((size_t)NN * DD);
    unsigned short* qkv = balloc((size_t)NN * QKVW);     // q|k|v interleaved
    unsigned short* elb = balloc((size_t)NEL * ED);
    unsigned short* e1b = balloc((size_t)NEL * ED);      // oe
    unsigned short* heb = balloc((size_t)NEL * ED);
    unsigned short* qeb = balloc((size_t)NEL * ED);
    unsigned short* fgb = balloc((size_t)NN * 4 * DD);   // 20.48M: FFN intermediate / o
    // aliases into the dead qkv region
    unsigned short* hb   = qkv;                          // h bf16       (5.12M)
    unsigned short* keve = qkv + (size_t)NN * DD;        // ke|ve bf16   (7.68M)
    unsigned short* ob   = fgb;                          // o bf16       (5.12M)
    // transposed bf16 weights
    unsigned short* WqkvT = balloc((size_t)NL * QKVW * DD);
    unsigned short* WoT  = balloc((size_t)NL * DD * DD);
    unsigned short* F1T  = balloc((size_t)NL * DD * 4 * DD);
    unsigned short* F2T  = balloc((size_t)NL * 4 * DD * DD);
    unsigned short* KVET = balloc((size_t)NL * 128 * 576);
    unsigned short* QET  = balloc((size_t)NL * 64 * 576);
    unsigned short* EoT  = balloc((size_t)NL * ED * ED);
    unsigned short* G1T  = balloc((size_t)NL * ED * 4 * ED);
    unsigned short* G2T  = balloc((size_t)NL * 4 * ED * ED);
    // CSR (ints)
    int* ip = (int*)(bp + ((boff + 63) & ~(size_t)63));
    size_t ioff = 0;
    auto ialloc = [&](size_t n) { int* p = ip + ioff; ioff += (n + 63) & ~(size_t)63; return p; };
    int* gcnt = ialloc(NN);
    int* goff = ialloc(NN);
    int* gcur = ialloc(NN);
    int* gord = ialloc(NE);
    int2* npack = (int2*)ialloc(2 * (size_t)NE);
    int* ecnt = ialloc(NEL);
    int* eoff = ialloc(NEL);
    int* ecur = ialloc(NEL);
    int* eord = ialloc(NLG);
    int* esrc = ialloc(NLG);
    int* bsum = ialloc(1024);

    // ---- weight prep (LDS-tiled transpose+cast) ----
    auto tt = [&](const float* src, unsigned short* dst, int K, int N,
                  long lstride, int rowStride, int rowOff, int colOff) {
        dim3 g(K / 32, N / 32, NL);
        ttrans_k<<<g, 256, 0, stream>>>(src, dst, K, N, lstride, rowStride, rowOff, colOff);
    };
    tt(Wq, WqkvT, 512, 512, (long)QKVW * DD, DD, 0, 0);
    tt(Wk, WqkvT, 512, 512, (long)QKVW * DD, DD, 512, 0);
    tt(Wv, WqkvT, 512, 512, (long)QKVW * DD, DD, 1024, 0);
    tt(Wo, WoT, 512, 512, (long)DD * DD, DD, 0, 0);
    tt(F1, F1T, 512, 2048, (long)DD * 4 * DD, DD, 0, 0);
    tt(F2, F2T, 2048, 512, (long)4 * DD * DD, 4 * DD, 0, 0);
    tt(Ek, KVET, 64, 64, (long)128 * 576, 576, 0, 0);
    tt(Nd, KVET, 512, 64, (long)128 * 576, 576, 0, 64);
    tt(Ev, KVET, 64, 64, (long)128 * 576, 576, 64, 0);
    tt(Nd, KVET, 512, 64, (long)128 * 576, 576, 64, 64);
    tt(Eq, QET, 64, 64, (long)64 * 576, 576, 0, 0);
    tt(Ns, QET, 512, 64, (long)64 * 576, 576, 0, 64);
    tt(Eo, EoT, 64, 64, (long)ED * ED, ED, 0, 0);
    tt(G1, G1T, 64, 256, (long)ED * 4 * ED, ED, 0, 0);
    tt(G2, G2T, 256, 64, (long)4 * ED * ED, 4 * ED, 0, 0);
    build_qkvb_k<<<(NL * QKVW + 255) / 256, 256, 0, stream>>>(bq, qkvb);
    ebias_k<<<(NL * 128 + 255) / 256, 256, 0, stream>>>(ndb, eqb, nsb, kvb, qb2);

    // ---- CSR build ----
    const int nbG = (NN + 255) / 256, nbE = (NEL + 255) / 256;
    zero_k<<<nbG, 256, 0, stream>>>((float*)gcnt, NN);
    hist_k<<<(NE + 255) / 256, 256, 0, stream>>>(g_dst, gcnt, NE);
    scanA_k<<<nbG, 256, 0, stream>>>(gcnt, goff, bsum, NN);
    scanB_k<<<1, 1024, 0, stream>>>(bsum, nbG);
    scanC_k<<<nbG, 256, 0, stream>>>(bsum, goff, gcur, NN);
    scatter_k<<<(NE + 255) / 256, 256, 0, stream>>>(g_dst, gcur, gord, NE);
    zero_k<<<nbE, 256, 0, stream>>>((float*)ecnt, NEL);
    hist_k<<<(NLG + 255) / 256, 256, 0, stream>>>(lg_dst, ecnt, NLG);
    scanA_k<<<nbE, 256, 0, stream>>>(ecnt, eoff, bsum, NEL);
    scanB_k<<<1, 1024, 0, stream>>>(bsum, nbE);
    scanC_k<<<nbE, 256, 0, stream>>>(bsum, eoff, ecur, NEL);
    scatter_k<<<(NLG + 255) / 256, 256, 0, stream>>>(lg_dst, ecur, eord, NLG);
    pack_k<<<(NLG + 255) / 256, 256, 0, stream>>>(gord, g_src, eord, lg_src, npack, esrc);

    const int ndD = NN * DD;
    const int elD = NEL * ED;
    castcopy_k<<<(ndD + 255) / 256, 256, 0, stream>>>(x_in, xbuf, xb, ndD);
    init_lg_k<<<(NE * ED + 255) / 256, 256, 0, stream>>>(rel, edge_feat, lgb);
    gather64_k<<<(elD + 255) / 256, 256, 0, stream>>>(lgb, local_index, el, elb);

    for (int i = 0; i < NL; ++i) {
        size_t oD2 = (size_t)i * DD * DD, oE2 = (size_t)i * ED * ED;

        // ---- node attention (reads lgb BEFORE this layer's edge update) ----
        run_gemm(stream, xb, WqkvT + (size_t)i * QKVW * DD, qkvb + (size_t)i * QKVW,
                 nullptr, nullptr, qkv, NN, DD, QKVW, 0);
        node_attn_csr_k<<<NN / 4, 256, 0, stream>>>(qkv, lgb, goff, npack, ob);
        // h = LN(x_in + o @ Wo + bo)
        run_gemm(stream, ob, WoT + oD2, bo + (size_t)i * DD, xbuf, t0, nullptr, NN, DD, DD, 0);
        ln_k<<<(NN + 3) / 4, 256, 0, stream>>>(t0, ln1g + (size_t)i * DD, ln1b + (size_t)i * DD,
                                               t0, DD, NN, hb, nullptr, nullptr);

        // ---- edge branch (fused split-K GEMMs) ----
        run_gemm2(stream, elb, xb, dst_ids, KVET + (size_t)i * 128 * 576,
                  kvb + (size_t)i * 128, keve, NEL, 576, 128, 64);
        run_gemm2(stream, elb, xb, src_ids, QET + (size_t)i * 64 * 576,
                  qb2 + (size_t)i * 64, qeb, NEL, 576, 64, 64);
        lg_attn_csr_k<<<NEL / 4, 256, 0, stream>>>(qeb, keve, eoff, esrc, e1b);
        // he = LN(el + oe @ Eo + eob)
        run_gemm(stream, e1b, EoT + oE2, eob + (size_t)i * ED, el, t2, nullptr, NEL, ED, ED, 0);
        ln_k<<<(NEL + 3) / 4, 256, 0, stream>>>(t2, eln1g + (size_t)i * ED, eln1b + (size_t)i * ED,
                                                t2, ED, NEL, heb, nullptr, nullptr);
        // edge FFN, single chunk
        run_gemm(stream, heb, G1T + (size_t)i * ED * 4 * ED, g1b + (size_t)i * 4 * ED,
                 nullptr, nullptr, fgb, NEL, ED, 4 * ED, 1);
        run_gemm(stream, fgb, G2T + (size_t)i * 4 * ED * ED, g2b + (size_t)i * ED,
                 t2, t3, nullptr, NEL, 4 * ED, ED, 0);
        // out_local = LN(...) -> el (f32) + elb (bf16) + scatter lgb[local_index]
        ln_k<<<(NEL + 3) / 4, 256, 0, stream>>>(t3, eln2g + (size_t)i * ED, eln2b + (size_t)i * ED,
                                                el, ED, NEL, elb, lgb, local_index);

        // ---- node FFN, single chunk (fgb = 10000x2048 bf16) ----
        run_gemm(stream, hb, F1T + (size_t)i * DD * 4 * DD, f1b + (size_t)i * 4 * DD,
                 nullptr, nullptr, fgb, NN, DD, 4 * DD, 1);
        run_gemm(stream, fgb, F2T + (size_t)i * 4 * DD * DD, f2b_ + (size_t)i * DD,
                 t0, xbuf, nullptr, NN, 2048, DD, 0);
        ln_k<<<(NN + 3) / 4, 256, 0, stream>>>(xbuf, ln2g + (size_t)i * DD, ln2b + (size_t)i * DD,
                                               xbuf, DD, NN, xb, nullptr, nullptr);
    }
    // outputs already in d_out
}

// Round 7
// 2138.478 us; speedup vs baseline: 3.7385x; 1.1849x over previous
//
#include <hip/hip_runtime.h>
#include <math.h>

#define NN   10000      // nodes
#define DD   512        // node dim
#define NH   8          // node heads (DK=64)
#define NE   120000     // edges (global)
#define NEL  60000      // local edges
#define NLG  600000     // line-graph edges
#define ED   64         // edge dim (EH=8, EDK=8)
#define NEH  8
#define NL   4          // layers
#define QKVW 1536       // fused q|k|v row width

typedef __attribute__((ext_vector_type(8))) short bf16x8;
typedef __attribute__((ext_vector_type(8))) unsigned short u16x8;
typedef __attribute__((ext_vector_type(4))) float f32x4;

__device__ __forceinline__ unsigned short f2b(float f) {
    union { float f; unsigned u; } c; c.f = f;
    unsigned u = c.u;
    unsigned r = u + 0x7FFFu + ((u >> 16) & 1u);
    return (unsigned short)(r >> 16);
}
__device__ __forceinline__ float b2f(unsigned short b) {
    union { unsigned u; float f; } c; c.u = ((unsigned)b) << 16;
    return c.f;
}

// ---------------- elementwise helpers ----------------
static __global__ __launch_bounds__(256)
void zero_k(float* __restrict__ p, int n) {
    int i = blockIdx.x * 256 + threadIdx.x;
    if (i < n) p[i] = 0.0f;
}

static __global__ __launch_bounds__(256)
void castcopy_k(const float* __restrict__ s, float* __restrict__ d,
                unsigned short* __restrict__ db, int n) {
    int i = blockIdx.x * 256 + threadIdx.x;
    if (i < n) { float v = s[i]; if (d) d[i] = v; db[i] = f2b(v); }
}

static __global__ __launch_bounds__(256)
void init_lg_k(const float* __restrict__ rel, const int* __restrict__ ef,
               unsigned short* __restrict__ lgb) {
    int i = blockIdx.x * 256 + threadIdx.x;
    if (i >= NE * ED) return;
    int e = i >> 6, c = i & 63;
    lgb[i] = f2b(rel[ef[e] * ED + c]);
}

static __global__ __launch_bounds__(256)
void gather64_k(const unsigned short* __restrict__ lgb, const int* __restrict__ idx,
                float* __restrict__ el, unsigned short* __restrict__ elb) {
    int i = blockIdx.x * 256 + threadIdx.x;
    if (i >= NEL * ED) return;
    int r = i >> 6;
    unsigned short b = lgb[(long)idx[r] * ED + (i & 63)];
    el[i] = b2f(b); elb[i] = b;
}

// ---------------- LDS-tiled transpose+cast ----------------
// in [l][K][N] f32 -> out[l*lstride + (rowOff+n)*rowStride + colOff + k] bf16
static __global__ __launch_bounds__(256)
void ttrans_k(const float* __restrict__ in, unsigned short* __restrict__ out,
              int K, int N, long lstride, int rowStride, int rowOff, int colOff) {
    __shared__ float sm[32][33];
    const int l = blockIdx.z;
    const int kt = blockIdx.x * 32, nt = blockIdx.y * 32;
    const int tx = threadIdx.x & 31, ty = threadIdx.x >> 5;   // ty 0..7
    const float* ip = in + (size_t)l * K * N;
    #pragma unroll
    for (int r = 0; r < 4; ++r)
        sm[ty + 8 * r][tx] = ip[(size_t)(kt + ty + 8 * r) * N + nt + tx];
    __syncthreads();
    unsigned short* op = out + (size_t)l * lstride;
    #pragma unroll
    for (int r = 0; r < 4; ++r) {
        int n = nt + ty + 8 * r;
        op[(size_t)(rowOff + n) * rowStride + colOff + kt + tx] = f2b(sm[tx][ty + 8 * r]);
    }
}

static __global__ __launch_bounds__(256)
void build_qkvb_k(const float* __restrict__ bq, float* __restrict__ out) {
    int i = blockIdx.x * 256 + threadIdx.x;
    if (i >= NL * QKVW) return;
    int l = i / QKVW, c = i - l * QKVW;
    out[i] = (c < 512) ? bq[l * 512 + c] : 0.0f;
}

// kvb[l*128+c] = ndb[l*64+(c&63)] ; qb2[l*64+c] = eqb+nsb
static __global__ __launch_bounds__(256)
void ebias_k(const float* __restrict__ ndb, const float* __restrict__ eqb,
             const float* __restrict__ nsb, float* __restrict__ kvb,
             float* __restrict__ qb2) {
    int i = blockIdx.x * 256 + threadIdx.x;
    if (i < NL * 128) kvb[i] = ndb[(i >> 7) * 64 + (i & 63)];
    if (i < NL * 64)  qb2[i] = eqb[i] + nsb[i];
}

// ---------------- CSR build ----------------
static __global__ __launch_bounds__(256)
void hist_k(const int* __restrict__ dst, int* __restrict__ cnt, int n) {
    int i = blockIdx.x * 256 + threadIdx.x;
    if (i < n) atomicAdd(&cnt[dst[i]], 1);
}

static __global__ __launch_bounds__(256)
void scanA_k(const int* __restrict__ cnt, int* __restrict__ off,
             int* __restrict__ bsum, int n) {
    __shared__ int sm[256];
    const int t = threadIdx.x;
    const int i = blockIdx.x * 256 + t;
    int v = (i < n) ? cnt[i] : 0;
    sm[t] = v; __syncthreads();
    int x = v;
    #pragma unroll
    for (int d = 1; d < 256; d <<= 1) {
        int y = (t >= d) ? sm[t - d] : 0;
        __syncthreads();
        x += y; sm[t] = x; __syncthreads();
    }
    if (i < n) off[i] = x - v;
    if (t == 255) bsum[blockIdx.x] = x;
}

static __global__ __launch_bounds__(1024)
void scanB_k(int* __restrict__ bsum, int nb) {
    __shared__ int sm[1024];
    const int t = threadIdx.x;
    int v = (t < nb) ? bsum[t] : 0;
    sm[t] = v; __syncthreads();
    int x = v;
    #pragma unroll
    for (int d = 1; d < 1024; d <<= 1) {
        int y = (t >= d) ? sm[t - d] : 0;
        __syncthreads();
        x += y; sm[t] = x; __syncthreads();
    }
    if (t < nb) bsum[t] = x - v;
}

static __global__ __launch_bounds__(256)
void scanC_k(const int* __restrict__ bsum, int* __restrict__ off,
             int* __restrict__ cur, int n) {
    int i = blockIdx.x * 256 + threadIdx.x;
    if (i < n) { int o = off[i] + bsum[blockIdx.x]; off[i] = o; cur[i] = o; }
}

static __global__ __launch_bounds__(256)
void scatter_k(const int* __restrict__ dst, int* __restrict__ cur,
               int* __restrict__ ord, int n) {
    int i = blockIdx.x * 256 + threadIdx.x;
    if (i < n) { int p = atomicAdd(&cur[dst[i]], 1); ord[p] = i; }
}

// flatten indirections: npack[j]=(e, gsrc[e]) ; esrc[j]=lsrc[eord[j]]
static __global__ __launch_bounds__(256)
void pack_k(const int* __restrict__ gord, const int* __restrict__ gsrc,
            const int* __restrict__ eord, const int* __restrict__ lsrc,
            int2* __restrict__ npack, int* __restrict__ esrc) {
    int i = blockIdx.x * 256 + threadIdx.x;
    if (i < NE) { int e = gord[i]; npack[i] = make_int2(e, gsrc[e]); }
    if (i < NLG) esrc[i] = lsrc[eord[i]];
}

// ---------------- bf16 MFMA GEMM, templated tile width, T14 pipeline -------
// If A2==null: C = A[M,K] @ Bt[Nc,K]^T.
// Else: A-row r = [ A[r][0:K1] | A2[idx2[r]][0:K-K1] ]  (A stride K1, A2 stride DD).
// BN=128: 4 waves each 64x64 (acc 4x4). BN=64: 4 waves each 64x32 (acc 4x2).
template<int BN>
static __global__ __launch_bounds__(256)
void gemm_bf16_k(const unsigned short* __restrict__ A,
                 const unsigned short* __restrict__ A2, const int* __restrict__ idx2,
                 const unsigned short* __restrict__ Bt, const float* __restrict__ bias,
                 const float* __restrict__ addC, float* __restrict__ C,
                 unsigned short* __restrict__ Cb,
                 int M, int K, int Nc, int doRelu, int K1)
{
    constexpr int NI = BN / 32;           // col frags per wave
    __shared__ unsigned short Asl[128 * 32];
    __shared__ unsigned short Bsl[BN * 32];
    const int tid  = threadIdx.x;
    const int lane = tid & 63;
    const int wave = tid >> 6;
    const int wr = (wave >> 1) * 64;
    const int wc = (wave & 1) * (BN / 2);

    // XCD-aware bijective block swizzle (m204): consecutive logical blocks
    // (same A row-panel) land on the same XCD's L2.
    const int nwg = gridDim.x * gridDim.y;
    const int hw = blockIdx.y * gridDim.x + blockIdx.x;
    const int q8 = nwg >> 3, r8 = nwg & 7;
    const int xcd = hw & 7, rest = hw >> 3;
    const int logical = (xcd < r8 ? xcd * (q8 + 1) : r8 * (q8 + 1) + (xcd - r8) * q8) + rest;
    const int bm = (logical / gridDim.x) * 128;
    const int bn = (logical % gridDim.x) * BN;

    const int row0 = tid >> 2;            // 0..63
    const int row1 = row0 + 64;
    const int slot = tid & 3;
    const int ss0 = slot ^ (row0 & 3) ^ ((row0 >> 2) & 3);
    const int ss1 = slot ^ (row1 & 3) ^ ((row1 >> 2) & 3);
    const int g0 = bm + row0, g1 = bm + row1;
    const bool v0 = g0 < M, v1 = g1 < M;
    long iR0 = 0, iR1 = 0;
    if (A2) { if (v0) iR0 = idx2[g0]; if (v1) iR1 = idx2[g1]; }
    const bool bv0 = bn + row0 < Nc;
    const bool bv1 = (BN == 128) && (bn + row1 < Nc);

    uint4 ra0, ra1, rb0, rb1;
    auto LOAD = [&](int k0) {
        const uint4 z4 = make_uint4(0u, 0u, 0u, 0u);
        ra0 = z4; ra1 = z4; rb0 = z4; rb1 = z4;
        const long koff = k0 + slot * 8;
        if (!A2) {
            if (v0) ra0 = *reinterpret_cast<const uint4*>(A + (long)g0 * K + koff);
            if (v1) ra1 = *reinterpret_cast<const uint4*>(A + (long)g1 * K + koff);
        } else if (k0 < K1) {
            if (v0) ra0 = *reinterpret_cast<const uint4*>(A + (long)g0 * K1 + koff);
            if (v1) ra1 = *reinterpret_cast<const uint4*>(A + (long)g1 * K1 + koff);
        } else {
            if (v0) ra0 = *reinterpret_cast<const uint4*>(A2 + iR0 * DD + (koff - K1));
            if (v1) ra1 = *reinterpret_cast<const uint4*>(A2 + iR1 * DD + (koff - K1));
        }
        if (bv0) rb0 = *reinterpret_cast<const uint4*>(Bt + (long)(bn + row0) * K + koff);
        if (BN == 128 && bv1) rb1 = *reinterpret_cast<const uint4*>(Bt + (long)(bn + row1) * K + koff);
    };

    f32x4 acc[4][NI] = {};
    const int rbase = lane & 15;
    const int ks = lane >> 4;

    LOAD(0);
    for (int k0 = 0; k0 < K; k0 += 32) {
        *reinterpret_cast<uint4*>(&Asl[row0 * 32 + ss0 * 8]) = ra0;
        *reinterpret_cast<uint4*>(&Asl[row1 * 32 + ss1 * 8]) = ra1;
        *reinterpret_cast<uint4*>(&Bsl[row0 * 32 + ss0 * 8]) = rb0;
        if (BN == 128)
            *reinterpret_cast<uint4*>(&Bsl[row1 * 32 + ss1 * 8]) = rb1;
        __syncthreads();
        if (k0 + 32 < K) LOAD(k0 + 32);   // T14: issue next-tile loads early;
                                          // latency hides under ds_read+MFMA

        bf16x8 af[4], bfr[NI];
        #pragma unroll
        for (int mi = 0; mi < 4; ++mi) {
            int r = wr + mi * 16 + rbase;
            int s = ks ^ (r & 3) ^ ((r >> 2) & 3);
            af[mi] = *reinterpret_cast<const bf16x8*>(&Asl[r * 32 + s * 8]);
        }
        #pragma unroll
        for (int ni = 0; ni < NI; ++ni) {
            int r = wc + ni * 16 + rbase;
            int s = ks ^ (r & 3) ^ ((r >> 2) & 3);
            bfr[ni] = *reinterpret_cast<const bf16x8*>(&Bsl[r * 32 + s * 8]);
        }
        #pragma unroll
        for (int mi = 0; mi < 4; ++mi)
            #pragma unroll
            for (int ni = 0; ni < NI; ++ni)
                acc[mi][ni] = __builtin_amdgcn_mfma_f32_16x16x32_bf16(
                    af[mi], bfr[ni], acc[mi][ni], 0, 0, 0);
        __syncthreads();
    }

    const int colBase = bn + wc + rbase;
    const int rowBase = bm + wr + ks * 4;
    #pragma unroll
    for (int mi = 0; mi < 4; ++mi) {
        #pragma unroll
        for (int j = 0; j < 4; ++j) {
            int r = rowBase + mi * 16 + j;
            if (r >= M) continue;
            long ro = (long)r * Nc;
            #pragma unroll
            for (int ni = 0; ni < NI; ++ni) {
                int cc = colBase + ni * 16;
                if (cc >= Nc) continue;
                float v = acc[mi][ni][j];
                if (bias)  v += bias[cc];
                if (doRelu) v = fmaxf(v, 0.0f);
                if (addC)  v += addC[ro + cc];
                if (Cb) Cb[ro + cc] = f2b(v);
                else    C[ro + cc] = v;
            }
        }
    }
}

// ---------------- LayerNorm (wave per row, 4 rows/block) ----------------
static __global__ __launch_bounds__(256)
void ln_k(const float* __restrict__ in, const float* __restrict__ g,
          const float* __restrict__ b, float* __restrict__ out, int Dw, int nrows,
          unsigned short* __restrict__ outb,
          unsigned short* __restrict__ out2b, const int* __restrict__ idx2)
{
    const int row = blockIdx.x * 4 + (threadIdx.x >> 6);
    if (row >= nrows) return;
    const int lane = threadIdx.x & 63;
    const int per = Dw >> 6;
    float v[8];
    const float* rp = in + (long)row * Dw;
    float s = 0.f;
    for (int i = 0; i < per; ++i) { v[i] = rp[i * 64 + lane]; s += v[i]; }
    #pragma unroll
    for (int off = 32; off; off >>= 1) s += __shfl_xor(s, off, 64);
    const float mu = s / (float)Dw;
    float var = 0.f;
    for (int i = 0; i < per; ++i) { float d = v[i] - mu; var += d * d; }
    #pragma unroll
    for (int off = 32; off; off >>= 1) var += __shfl_xor(var, off, 64);
    const float rstd = rsqrtf(var / (float)Dw + 1e-5f);
    for (int i = 0; i < per; ++i) {
        int c = i * 64 + lane;
        float o = (v[i] - mu) * rstd * g[c] + b[c];
        out[(long)row * Dw + c] = o;
        if (outb)  outb[(long)row * Dw + c] = f2b(o);
        if (out2b) out2b[(long)idx2[row] * Dw + c] = f2b(o);
    }
}

// ---------------- node attention, CSR, 2-way unrolled ----------------
static __global__ __launch_bounds__(256)
void node_attn_csr_k(const unsigned short* __restrict__ qkv,
                     const unsigned short* __restrict__ lgb,
                     const int* __restrict__ goff, const int2* __restrict__ npack,
                     unsigned short* __restrict__ ob)
{
    int node = blockIdx.x * 4 + (threadIdx.x >> 6);
    if (node >= NN) return;
    const int lane = threadIdx.x & 63;
    float qv[8];
    {
        u16x8 q8 = *reinterpret_cast<const u16x8*>(qkv + (long)node * QKVW + lane * 8);
        #pragma unroll
        for (int i = 0; i < 8; ++i) qv[i] = b2f(q8[i]);
    }
    float wva[8] = {0.f, 0.f, 0.f, 0.f, 0.f, 0.f, 0.f, 0.f};
    float zac = 0.f;
    int j = goff[node];
    const int hi = (node + 1 < NN) ? goff[node + 1] : NE;
    const int eoffl = (lane & 7) * 8;

    for (; j + 2 <= hi; j += 2) {
        int2 pa = npack[j], pb = npack[j + 1];
        u16x8 kA = *reinterpret_cast<const u16x8*>(qkv + (long)pa.y * QKVW + 512 + lane * 8);
        u16x8 vA = *reinterpret_cast<const u16x8*>(qkv + (long)pa.y * QKVW + 1024 + lane * 8);
        u16x8 eA = *reinterpret_cast<const u16x8*>(lgb + (long)pa.x * ED + eoffl);
        u16x8 kB = *reinterpret_cast<const u16x8*>(qkv + (long)pb.y * QKVW + 512 + lane * 8);
        u16x8 vB = *reinterpret_cast<const u16x8*>(qkv + (long)pb.y * QKVW + 1024 + lane * 8);
        u16x8 eB = *reinterpret_cast<const u16x8*>(lgb + (long)pb.x * ED + eoffl);
        float edA[8], vvA[8], edB[8], vvB[8];
        float pA = 0.f, pB = 0.f;
        #pragma unroll
        for (int i = 0; i < 8; ++i) {
            edA[i] = b2f(eA[i]); vvA[i] = b2f(vA[i]);
            pA = fmaf(b2f(kA[i]) + edA[i], qv[i], pA);
            edB[i] = b2f(eB[i]); vvB[i] = b2f(vB[i]);
            pB = fmaf(b2f(kB[i]) + edB[i], qv[i], pB);
        }
        pA += __shfl_xor(pA, 1, 64); pA += __shfl_xor(pA, 2, 64); pA += __shfl_xor(pA, 4, 64);
        pB += __shfl_xor(pB, 1, 64); pB += __shfl_xor(pB, 2, 64); pB += __shfl_xor(pB, 4, 64);
        float wA = expf(fminf(fmaxf(pA * 0.125f, -10.0f), 10.0f));
        float wB = expf(fminf(fmaxf(pB * 0.125f, -10.0f), 10.0f));
        #pragma unroll
        for (int i = 0; i < 8; ++i) {
            wva[i] = fmaf(wA, vvA[i] + edA[i], wva[i]);
            wva[i] = fmaf(wB, vvB[i] + edB[i], wva[i]);
        }
        zac += wA + wB;
    }
    for (; j < hi; ++j) {
        int2 pa = npack[j];
        u16x8 kA = *reinterpret_cast<const u16x8*>(qkv + (long)pa.y * QKVW + 512 + lane * 8);
        u16x8 vA = *reinterpret_cast<const u16x8*>(qkv + (long)pa.y * QKVW + 1024 + lane * 8);
        u16x8 eA = *reinterpret_cast<const u16x8*>(lgb + (long)pa.x * ED + eoffl);
        float edA[8], vvA[8];
        float pA = 0.f;
        #pragma unroll
        for (int i = 0; i < 8; ++i) {
            edA[i] = b2f(eA[i]); vvA[i] = b2f(vA[i]);
            pA = fmaf(b2f(kA[i]) + edA[i], qv[i], pA);
        }
        pA += __shfl_xor(pA, 1, 64); pA += __shfl_xor(pA, 2, 64); pA += __shfl_xor(pA, 4, 64);
        float wA = expf(fminf(fmaxf(pA * 0.125f, -10.0f), 10.0f));
        #pragma unroll
        for (int i = 0; i < 8; ++i) wva[i] = fmaf(wA, vvA[i] + edA[i], wva[i]);
        zac += wA;
    }
    const float inv = 1.0f / fmaxf(zac, 1e-9f);
    u16x8 o8;
    #pragma unroll
    for (int i = 0; i < 8; ++i) o8[i] = f2b(wva[i] * inv);
    *reinterpret_cast<u16x8*>(ob + (long)node * DD + lane * 8) = o8;
}

// ---------------- line-graph attention, CSR, 4-way unrolled ----------------
// keve interleaved rows [m][128] = ke|ve
static __global__ __launch_bounds__(256)
void lg_attn_csr_k(const unsigned short* __restrict__ qeb,
                   const unsigned short* __restrict__ keve,
                   const int* __restrict__ eoff, const int* __restrict__ esrc,
                   unsigned short* __restrict__ oeb)
{
    int d = blockIdx.x * 4 + (threadIdx.x >> 6);
    if (d >= NEL) return;
    const int lane = threadIdx.x & 63;
    const float qv = b2f(qeb[(long)d * ED + lane]);
    float oa = 0.f, zac = 0.f;
    int j = eoff[d];
    const int hi = (d + 1 < NEL) ? eoff[d + 1] : NLG;
    for (; j + 4 <= hi; j += 4) {
        int ss[4]; float kk[4], vv[4];
        #pragma unroll
        for (int u = 0; u < 4; ++u) ss[u] = esrc[j + u];
        #pragma unroll
        for (int u = 0; u < 4; ++u) {
            kk[u] = b2f(keve[(long)ss[u] * 128 + lane]);
            vv[u] = b2f(keve[(long)ss[u] * 128 + 64 + lane]);
        }
        #pragma unroll
        for (int u = 0; u < 4; ++u) {
            float p = kk[u] * qv;
            p += __shfl_xor(p, 1, 64); p += __shfl_xor(p, 2, 64); p += __shfl_xor(p, 4, 64);
            float w = expf(fminf(fmaxf(p * 0.35355339059327373f, -10.0f), 10.0f));
            oa = fmaf(w, vv[u], oa);
            zac += w;
        }
    }
    for (; j < hi; ++j) {
        int s = esrc[j];
        float kv = b2f(keve[(long)s * 128 + lane]);
        float vv = b2f(keve[(long)s * 128 + 64 + lane]);
        float p = kv * qv;
        p += __shfl_xor(p, 1, 64); p += __shfl_xor(p, 2, 64); p += __shfl_xor(p, 4, 64);
        float w = expf(fminf(fmaxf(p * 0.35355339059327373f, -10.0f), 10.0f));
        oa = fmaf(w, vv, oa);
        zac += w;
    }
    oeb[(long)d * ED + lane] = f2b(oa / fmaxf(zac, 1e-9f));
}

// ---------------- host ----------------
static inline void run_gemm(hipStream_t st, const unsigned short* A,
                            const unsigned short* Bt, const float* bias,
                            const float* addC, float* C, unsigned short* Cb,
                            int M, int K, int Nc, int relu, bool narrow)
{
    if (narrow) {
        dim3 g((Nc + 63) / 64, (M + 127) / 128);
        gemm_bf16_k<64><<<g, 256, 0, st>>>(A, nullptr, nullptr, Bt, bias, addC, C, Cb, M, K, Nc, relu, 0);
    } else {
        dim3 g((Nc + 127) / 128, (M + 127) / 128);
        gemm_bf16_k<128><<<g, 256, 0, st>>>(A, nullptr, nullptr, Bt, bias, addC, C, Cb, M, K, Nc, relu, 0);
    }
}
static inline void run_gemm2(hipStream_t st, const unsigned short* A1,
                             const unsigned short* A2, const int* idx2,
                             const unsigned short* Bt, const float* bias,
                             unsigned short* Cb, int M, int K, int Nc, int K1, bool narrow)
{
    if (narrow) {
        dim3 g((Nc + 63) / 64, (M + 127) / 128);
        gemm_bf16_k<64><<<g, 256, 0, st>>>(A1, A2, idx2, Bt, bias, nullptr, nullptr, Cb, M, K, Nc, 0, K1);
    } else {
        dim3 g((Nc + 127) / 128, (M + 127) / 128);
        gemm_bf16_k<128><<<g, 256, 0, st>>>(A1, A2, idx2, Bt, bias, nullptr, nullptr, Cb, M, K, Nc, 0, K1);
    }
}

extern "C" void kernel_launch(void* const* d_in, const int* in_sizes, int n_in,
                              void* d_out, int out_size, void* d_ws, size_t ws_size,
                              hipStream_t stream)
{
    const float* x_in  = (const float*)d_in[0];
    const float* rel   = (const float*)d_in[1];
    const float* Wq    = (const float*)d_in[2];
    const float* bq    = (const float*)d_in[3];
    const float* Wk    = (const float*)d_in[4];
    const float* Wv    = (const float*)d_in[5];
    const float* Wo    = (const float*)d_in[6];
    const float* bo    = (const float*)d_in[7];
    const float* ln1g  = (const float*)d_in[8];
    const float* ln1b  = (const float*)d_in[9];
    const float* F1    = (const float*)d_in[10];
    const float* f1b   = (const float*)d_in[11];
    const float* F2    = (const float*)d_in[12];
    const float* f2b_  = (const float*)d_in[13];
    const float* ln2g  = (const float*)d_in[14];
    const float* ln2b  = (const float*)d_in[15];
    const float* Eq    = (const float*)d_in[16];
    const float* eqb   = (const float*)d_in[17];
    const float* Ek    = (const float*)d_in[18];
    const float* Ev    = (const float*)d_in[19];
    const float* Eo    = (const float*)d_in[20];
    const float* eob   = (const float*)d_in[21];
    const float* Ns    = (const float*)d_in[22];
    const float* nsb   = (const float*)d_in[23];
    const float* Nd    = (const float*)d_in[24];
    const float* ndb   = (const float*)d_in[25];
    const float* eln1g = (const float*)d_in[26];
    const float* eln1b = (const float*)d_in[27];
    const float* G1    = (const float*)d_in[28];
    const float* g1b   = (const float*)d_in[29];
    const float* G2    = (const float*)d_in[30];
    const float* g2b   = (const float*)d_in[31];
    const float* eln2g = (const float*)d_in[32];
    const float* eln2b = (const float*)d_in[33];
    const int* edge_feat   = (const int*)d_in[34];
    const int* local_index = (const int*)d_in[35];
    const int* src_ids     = (const int*)d_in[36];
    const int* dst_ids     = (const int*)d_in[37];
    const int* g_src       = (const int*)d_in[38];
    const int* g_dst       = (const int*)d_in[39];
    const int* lg_src      = (const int*)d_in[40];
    const int* lg_dst      = (const int*)d_in[41];

    // outputs live in d_out
    float* xbuf = (float*)d_out;                   // (NN, DD)
    float* el   = xbuf + (size_t)NN * DD;          // (NEL, ED)

    // ---- workspace layout (~214 MB) ----
    float* W = (float*)d_ws;
    size_t off = 0;
    auto alloc = [&](size_t n) { float* p = W + off; off += (n + 63) & ~(size_t)63; return p; };
    float* t0  = alloc((size_t)NN * DD);     // h pre-LN
    float* t2  = alloc((size_t)NEL * ED);    // he pre-LN
    float* t3  = alloc((size_t)NEL * ED);    // edge FFN out pre-LN
    float* qkvb = alloc((size_t)NL * QKVW);  // fused qkv bias
    float* kvb  = alloc((size_t)NL * 128);   // ke|ve bias
    float* qb2  = alloc((size_t)NL * ED);    // qe bias (eqb+nsb)

    unsigned short* bp = (unsigned short*)(W + off);
    size_t boff = 0;
    auto balloc = [&](size_t n) { unsigned short* p = bp + boff; boff += (n + 63) & ~(size_t)63; return p; };
    unsigned short* lgb = balloc((size_t)NE * ED);
    unsigned short* xb  = balloc((size_t)NN * DD);
    unsigned short* qkv = balloc((size_t)NN * QKVW);     // q|k|v interleaved
    unsigned short* elb = balloc((size_t)NEL * ED);
    unsigned short* e1b = balloc((size_t)NEL * ED);      // oe
    unsigned short* heb = balloc((size_t)NEL * ED);
    unsigned short* qeb = balloc((size_t)NEL * ED);
    unsigned short* fgb = balloc((size_t)NN * 4 * DD);   // 20.48M: FFN intermediate / o
    // aliases into the dead qkv region
    unsigned short* hb   = qkv;                          // h bf16       (5.12M)
    unsigned short* keve = qkv + (size_t)NN * DD;        // ke|ve bf16   (7.68M)
    unsigned short* ob   = fgb;                          // o bf16       (5.12M)
    // transposed bf16 weights
    unsigned short* WqkvT = balloc((size_t)NL * QKVW * DD);
    unsigned short* WoT  = balloc((size_t)NL * DD * DD);
    unsigned short* F1T  = balloc((size_t)NL * DD * 4 * DD);
    unsigned short* F2T  = balloc((size_t)NL * 4 * DD * DD);
    unsigned short* KVET = balloc((size_t)NL * 128 * 576);
    unsigned short* QET  = balloc((size_t)NL * 64 * 576);
    unsigned short* EoT  = balloc((size_t)NL * ED * ED);
    unsigned short* G1T  = balloc((size_t)NL * ED * 4 * ED);
    unsigned short* G2T  = balloc((size_t)NL * 4 * ED * ED);
    // CSR (ints)
    int* ip = (int*)(bp + ((boff + 63) & ~(size_t)63));
    size_t ioff = 0;
    auto ialloc = [&](size_t n) { int* p = ip + ioff; ioff += (n + 63) & ~(size_t)63; return p; };
    int* gcnt = ialloc(NN);
    int* goff = ialloc(NN);
    int* gcur = ialloc(NN);
    int* gord = ialloc(NE);
    int2* npack = (int2*)ialloc(2 * (size_t)NE);
    int* ecnt = ialloc(NEL);
    int* eoff = ialloc(NEL);
    int* ecur = ialloc(NEL);
    int* eord = ialloc(NLG);
    int* esrc = ialloc(NLG);
    int* bsum = ialloc(1024);

    // ---- weight prep (LDS-tiled transpose+cast) ----
    auto tt = [&](const float* src, unsigned short* dst, int K, int N,
                  long lstride, int rowStride, int rowOff, int colOff) {
        dim3 g(K / 32, N / 32, NL);
        ttrans_k<<<g, 256, 0, stream>>>(src, dst, K, N, lstride, rowStride, rowOff, colOff);
    };
    tt(Wq, WqkvT, 512, 512, (long)QKVW * DD, DD, 0, 0);
    tt(Wk, WqkvT, 512, 512, (long)QKVW * DD, DD, 512, 0);
    tt(Wv, WqkvT, 512, 512, (long)QKVW * DD, DD, 1024, 0);
    tt(Wo, WoT, 512, 512, (long)DD * DD, DD, 0, 0);
    tt(F1, F1T, 512, 2048, (long)DD * 4 * DD, DD, 0, 0);
    tt(F2, F2T, 2048, 512, (long)4 * DD * DD, 4 * DD, 0, 0);
    tt(Ek, KVET, 64, 64, (long)128 * 576, 576, 0, 0);
    tt(Nd, KVET, 512, 64, (long)128 * 576, 576, 0, 64);
    tt(Ev, KVET, 64, 64, (long)128 * 576, 576, 64, 0);
    tt(Nd, KVET, 512, 64, (long)128 * 576, 576, 64, 64);
    tt(Eq, QET, 64, 64, (long)64 * 576, 576, 0, 0);
    tt(Ns, QET, 512, 64, (long)64 * 576, 576, 0, 64);
    tt(Eo, EoT, 64, 64, (long)ED * ED, ED, 0, 0);
    tt(G1, G1T, 64, 256, (long)ED * 4 * ED, ED, 0, 0);
    tt(G2, G2T, 256, 64, (long)4 * ED * ED, 4 * ED, 0, 0);
    build_qkvb_k<<<(NL * QKVW + 255) / 256, 256, 0, stream>>>(bq, qkvb);
    ebias_k<<<(NL * 128 + 255) / 256, 256, 0, stream>>>(ndb, eqb, nsb, kvb, qb2);

    // ---- CSR build ----
    const int nbG = (NN + 255) / 256, nbE = (NEL + 255) / 256;
    zero_k<<<nbG, 256, 0, stream>>>((float*)gcnt, NN);
    hist_k<<<(NE + 255) / 256, 256, 0, stream>>>(g_dst, gcnt, NE);
    scanA_k<<<nbG, 256, 0, stream>>>(gcnt, goff, bsum, NN);
    scanB_k<<<1, 1024, 0, stream>>>(bsum, nbG);
    scanC_k<<<nbG, 256, 0, stream>>>(bsum, goff, gcur, NN);
    scatter_k<<<(NE + 255) / 256, 256, 0, stream>>>(g_dst, gcur, gord, NE);
    zero_k<<<nbE, 256, 0, stream>>>((float*)ecnt, NEL);
    hist_k<<<(NLG + 255) / 256, 256, 0, stream>>>(lg_dst, ecnt, NLG);
    scanA_k<<<nbE, 256, 0, stream>>>(ecnt, eoff, bsum, NEL);
    scanB_k<<<1, 1024, 0, stream>>>(bsum, nbE);
    scanC_k<<<nbE, 256, 0, stream>>>(bsum, eoff, ecur, NEL);
    scatter_k<<<(NLG + 255) / 256, 256, 0, stream>>>(lg_dst, ecur, eord, NLG);
    pack_k<<<(NLG + 255) / 256, 256, 0, stream>>>(gord, g_src, eord, lg_src, npack, esrc);

    const int ndD = NN * DD;
    const int elD = NEL * ED;
    castcopy_k<<<(ndD + 255) / 256, 256, 0, stream>>>(x_in, xbuf, xb, ndD);
    init_lg_k<<<(NE * ED + 255) / 256, 256, 0, stream>>>(rel, edge_feat, lgb);
    gather64_k<<<(elD + 255) / 256, 256, 0, stream>>>(lgb, local_index, el, elb);

    for (int i = 0; i < NL; ++i) {
        size_t oD2 = (size_t)i * DD * DD, oE2 = (size_t)i * ED * ED;

        // ---- node attention (reads lgb BEFORE this layer's edge update) ----
        run_gemm(stream, xb, WqkvT + (size_t)i * QKVW * DD, qkvb + (size_t)i * QKVW,
                 nullptr, nullptr, qkv, NN, DD, QKVW, 0, false);
        node_attn_csr_k<<<NN / 4, 256, 0, stream>>>(qkv, lgb, goff, npack, ob);
        // h = LN(x_in + o @ Wo + bo)
        run_gemm(stream, ob, WoT + oD2, bo + (size_t)i * DD, xbuf, t0, nullptr, NN, DD, DD, 0, true);
        ln_k<<<(NN + 3) / 4, 256, 0, stream>>>(t0, ln1g + (size_t)i * DD, ln1b + (size_t)i * DD,
                                               t0, DD, NN, hb, nullptr, nullptr);

        // ---- edge branch (fused split-K GEMMs) ----
        run_gemm2(stream, elb, xb, dst_ids, KVET + (size_t)i * 128 * 576,
                  kvb + (size_t)i * 128, keve, NEL, 576, 128, 64, true);
        run_gemm2(stream, elb, xb, src_ids, QET + (size_t)i * 64 * 576,
                  qb2 + (size_t)i * 64, qeb, NEL, 576, 64, 64, true);
        lg_attn_csr_k<<<NEL / 4, 256, 0, stream>>>(qeb, keve, eoff, esrc, e1b);
        // he = LN(el + oe @ Eo + eob)
        run_gemm(stream, e1b, EoT + oE2, eob + (size_t)i * ED, el, t2, nullptr, NEL, ED, ED, 0, true);
        ln_k<<<(NEL + 3) / 4, 256, 0, stream>>>(t2, eln1g + (size_t)i * ED, eln1b + (size_t)i * ED,
                                                t2, ED, NEL, heb, nullptr, nullptr);
        // edge FFN, single chunk
        run_gemm(stream, heb, G1T + (size_t)i * ED * 4 * ED, g1b + (size_t)i * 4 * ED,
                 nullptr, nullptr, fgb, NEL, ED, 4 * ED, 1, false);
        run_gemm(stream, fgb, G2T + (size_t)i * 4 * ED * ED, g2b + (size_t)i * ED,
                 t2, t3, nullptr, NEL, 4 * ED, ED, 0, true);
        // out_local = LN(...) -> el (f32) + elb (bf16) + scatter lgb[local_index]
        ln_k<<<(NEL + 3) / 4, 256, 0, stream>>>(t3, eln2g + (size_t)i * ED, eln2b + (size_t)i * ED,
                                                el, ED, NEL, elb, lgb, local_index);

        // ---- node FFN, single chunk (fgb = 10000x2048 bf16) ----
        run_gemm(stream, hb, F1T + (size_t)i * DD * 4 * DD, f1b + (size_t)i * 4 * DD,
                 nullptr, nullptr, fgb, NN, DD, 4 * DD, 1, false);
        run_gemm(stream, fgb, F2T + (size_t)i * 4 * DD * DD, f2b_ + (size_t)i * DD,
                 t0, xbuf, nullptr, NN, 2048, DD, 0, true);
        ln_k<<<(NN + 3) / 4, 256, 0, stream>>>(xbuf, ln2g + (size_t)i * DD, ln2b + (size_t)i * DD,
                                               xbuf, DD, NN, xb, nullptr, nullptr);
    }
    // outputs already in d_out
}